// Round 1
// baseline (896.054 us; speedup 1.0000x reference)
//
#include <hip/hip_runtime.h>
#include <math.h>

typedef __bf16 bf16;
typedef bf16 bf16x8 __attribute__((ext_vector_type(8)));
typedef float f32x4 __attribute__((ext_vector_type(4)));

#define T_DIM 1024
#define H_DIM 1024
#define E_NUM 64
#define I_DIM 512
#define KTOP 6
#define TKG 3
#define CAP 256
#define A_TOT (T_DIM * KTOP)
#define SCALE_F 2.5f

#define BM 32
#define BN 256
#define BK 32
#define LDP 40  // padded LDS k-stride (bf16 elems): conflict-free ds_read_b128

// ---------------------------------------------------------------- convert x -> bf16
__global__ __launch_bounds__(256) void cvt_bf16(const float* __restrict__ in,
                                                bf16* __restrict__ out) {
  int i = (blockIdx.x * 256 + threadIdx.x) * 4;
  float4 v = *(const float4*)(in + i);
  bf16 __align__(8) t[4] = {(bf16)v.x, (bf16)v.y, (bf16)v.z, (bf16)v.w};
  *(uint2*)(out + i) = *(const uint2*)t;
}

// ---------------------------------------------------------------- router + grouped top-k
__global__ __launch_bounds__(256) void router_topk(const float* __restrict__ x,
                                                   const float* __restrict__ gw,
                                                   const float* __restrict__ bias,
                                                   int* __restrict__ topk_id,
                                                   float* __restrict__ topk_w) {
  __shared__ float part[4][64];
  const int t = blockIdx.x;
  const int tid = threadIdx.x;
  const int wave = tid >> 6, lane = tid & 63;
  const float* xr = x + (long)t * H_DIM + wave * 256;
  float acc = 0.f;
  for (int h = 0; h < 256; h += 4) {
    float4 xv = *(const float4*)(xr + h);
    int hh = wave * 256 + h;
    acc += xv.x * gw[(hh + 0) * E_NUM + lane];
    acc += xv.y * gw[(hh + 1) * E_NUM + lane];
    acc += xv.z * gw[(hh + 2) * E_NUM + lane];
    acc += xv.w * gw[(hh + 3) * E_NUM + lane];
  }
  part[wave][lane] = acc;
  __syncthreads();
  if (wave != 0) return;
  acc = part[0][lane] + part[1][lane] + part[2][lane] + part[3][lane];

  float score = 1.f / (1.f + __expf(-acc));  // sigmoid (weights come from this)
  float sel = score + bias[lane];            // biased score (selection only)

  // top-2 within each group of 8 lanes (butterfly merge of (m1,m2) pairs)
  float m1 = sel, m2 = -INFINITY;
  #pragma unroll
  for (int off = 1; off < 8; off <<= 1) {
    float o1 = __shfl_xor(m1, off);
    float o2 = __shfl_xor(m2, off);
    float mn = fminf(m1, o1);
    float alt = (m1 >= o1) ? m2 : o2;
    m1 = fmaxf(m1, o1);
    m2 = fmaxf(mn, alt);
  }
  float gscore = m1 + m2;

  // top-3 groups (argmax with lowest-index tiebreak, 3 rounds)
  const int my_g = lane >> 3;
  unsigned gmask = 0;
  float gv = ((lane & 7) == 0) ? gscore : -INFINITY;
  for (int r = 0; r < TKG; ++r) {
    float v = gv;
    int idx = my_g;
    #pragma unroll
    for (int off = 1; off < 64; off <<= 1) {
      float ov = __shfl_xor(v, off);
      int oi = __shfl_xor(idx, off);
      if (ov > v || (ov == v && oi < idx)) { v = ov; idx = oi; }
    }
    gmask |= 1u << idx;
    if (my_g == idx) gv = -INFINITY;
  }

  // top-6 experts within selected groups
  float cand = ((gmask >> my_g) & 1u) ? sel : -INFINITY;
  float wk[KTOP];
  int ik[KTOP];
  float wsum = 0.f;
  for (int r = 0; r < KTOP; ++r) {
    float v = cand;
    int idx = lane;
    #pragma unroll
    for (int off = 1; off < 64; off <<= 1) {
      float ov = __shfl_xor(v, off);
      int oi = __shfl_xor(idx, off);
      if (ov > v || (ov == v && oi < idx)) { v = ov; idx = oi; }
    }
    float w = __shfl(score, idx);  // weight from UN-biased score
    wk[r] = w; ik[r] = idx; wsum += w;
    if (lane == idx) cand = -INFINITY;
  }
  if (lane == 0) {
    float inv = 1.f / wsum;
    #pragma unroll
    for (int r = 0; r < KTOP; ++r) {
      topk_id[t * KTOP + r] = ik[r];
      topk_w[t * KTOP + r] = wk[r] * inv;
    }
  }
}

// ---------------------------------------------------------------- dispatch (ordered compaction)
__global__ __launch_bounds__(64) void dispatch(const int* __restrict__ topk_id,
                                               int* __restrict__ rowlist,
                                               int* __restrict__ slot_a,
                                               int* __restrict__ counts) {
  __shared__ int ids[A_TOT];
  const int e = blockIdx.x, lane = threadIdx.x;
  for (int i = lane; i < A_TOT; i += 64) ids[i] = topk_id[i];
  __syncthreads();
  int base = 0;
  for (int a0 = 0; a0 < A_TOT; a0 += 64) {
    int a = a0 + lane;
    bool m = (ids[a] == e);
    unsigned long long bal = __ballot(m);
    if (m) {
      int pos = base + __popcll(bal & ((1ull << lane) - 1ull));
      slot_a[a] = (pos < CAP) ? pos : -1;
      if (pos < CAP) rowlist[e * CAP + pos] = a;
    }
    base += __popcll(bal);
  }
  if (lane == 0) counts[e] = (base < CAP) ? base : CAP;
}

// ---------------------------------------------------------------- gate_up GEMM + SiLU*mul
struct __align__(16) SmemGU {
  union {
    struct { bf16 A[BM * LDP]; bf16 Bt[BN * LDP]; } k;
    float gu[BM * BN];
  } u;
};

__global__ __launch_bounds__(256) void gemm_gu(
    const bf16* __restrict__ Abase, int a_ld,
    const int* __restrict__ rows, const int* __restrict__ counts, int n_rows_fixed,
    const float* __restrict__ Bbase, int ldb, long b_estride, int u_off,
    bf16* __restrict__ actout, int act_ld, long act_estride, int kdim) {
  __shared__ SmemGU sm;
  const int e = blockIdx.z;
  const int n_rows = counts ? counts[e] : n_rows_fixed;
  const int m0 = blockIdx.x * BM;
  if (m0 >= n_rows) return;
  const int nb = blockIdx.y;
  const int tid = threadIdx.x;
  const int wave = tid >> 6, lane = tid & 63;
  const int q = lane >> 4, l16 = lane & 15;
  const int m_base = (wave & 1) * 16;
  const int n_base = (wave >> 1) * 128;

  const int ar = tid >> 3;
  const int ac = (tid & 7) * 4;
  const bool avalid = (m0 + ar) < n_rows;
  const bf16* aptr = Abase;
  if (avalid) {
    int grow = rows ? (rows[e * CAP + m0 + ar] / KTOP) : (m0 + ar);
    aptr = Abase + (long)grow * a_ld + ac;
  }
  // column f = tid: first 128 = gate cols, next 128 = up cols (pairing for fused silu)
  const int fcol = (tid < 128) ? (nb * 128 + tid) : (u_off + nb * 128 + (tid - 128));
  const float* bptr = Bbase + (long)e * b_estride + fcol;

  f32x4 acc[8];
  const f32x4 z = {0.f, 0.f, 0.f, 0.f};
  #pragma unroll
  for (int i = 0; i < 8; ++i) acc[i] = z;

  for (int k0 = 0; k0 < kdim; k0 += BK) {
    uint2 av = {0u, 0u};
    if (avalid) av = *(const uint2*)aptr;
    *(uint2*)(sm.u.k.A + ar * LDP + ac) = av;
    #pragma unroll
    for (int v = 0; v < 8; ++v) {
      float b0 = bptr[(long)(v * 4 + 0) * ldb];
      float b1 = bptr[(long)(v * 4 + 1) * ldb];
      float b2 = bptr[(long)(v * 4 + 2) * ldb];
      float b3 = bptr[(long)(v * 4 + 3) * ldb];
      bf16 __align__(8) tb[4] = {(bf16)b0, (bf16)b1, (bf16)b2, (bf16)b3};
      *(uint2*)(sm.u.k.Bt + tid * LDP + v * 4) = *(const uint2*)tb;
    }
    __syncthreads();
    bf16x8 af = *(const bf16x8*)(sm.u.k.A + (m_base + l16) * LDP + q * 8);
    #pragma unroll
    for (int nt = 0; nt < 8; ++nt) {
      bf16x8 bfv = *(const bf16x8*)(sm.u.k.Bt + (n_base + nt * 16 + l16) * LDP + q * 8);
      acc[nt] = __builtin_amdgcn_mfma_f32_16x16x32_bf16(af, bfv, acc[nt], 0, 0, 0);
    }
    __syncthreads();
    aptr += BK;
    bptr += (long)BK * ldb;
  }

  // D layout: col = lane&15, row = (lane>>4)*4 + reg  [m89-verified]
  #pragma unroll
  for (int nt = 0; nt < 8; ++nt)
    #pragma unroll
    for (int r = 0; r < 4; ++r)
      sm.u.gu[(m_base + q * 4 + r) * BN + n_base + nt * 16 + l16] = acc[nt][r];
  __syncthreads();

  const int rr = tid >> 3;
  const int i0 = (tid & 7) * 16;
  bf16 __align__(16) tmp[16];
  #pragma unroll
  for (int j = 0; j < 16; ++j) {
    float g = sm.u.gu[rr * BN + i0 + j];
    float uu = sm.u.gu[rr * BN + 128 + i0 + j];
    float s = g / (1.f + __expf(-g));
    tmp[j] = (bf16)(s * uu);
  }
  long ob = (long)e * act_estride + (long)(m0 + rr) * act_ld + nb * 128 + i0;
  *(uint4*)(actout + ob) = *(const uint4*)tmp;
  *(uint4*)(actout + ob + 8) = *((const uint4*)tmp + 1);
}

// ---------------------------------------------------------------- down GEMM
struct __align__(16) SmemK {
  bf16 A[BM * LDP];
  bf16 Bt[BN * LDP];
};

template <typename OutT>
__global__ __launch_bounds__(256) void gemm_down(
    const bf16* __restrict__ Abase, long a_estride, int a_ld,
    const int* __restrict__ counts, int n_rows_fixed,
    const float* __restrict__ Bbase, long b_estride, int ldb,
    OutT* __restrict__ Out, long out_estride, int out_ld, int kdim) {
  __shared__ SmemK sm;
  const int e = blockIdx.z;
  const int n_rows = counts ? counts[e] : n_rows_fixed;
  const int m0 = blockIdx.x * BM;
  if (m0 >= n_rows) return;
  const int nb = blockIdx.y;
  const int tid = threadIdx.x;
  const int wave = tid >> 6, lane = tid & 63;
  const int q = lane >> 4, l16 = lane & 15;
  const int m_base = (wave & 1) * 16;
  const int n_base = (wave >> 1) * 128;

  const int ar = tid >> 3;
  const int ac = (tid & 7) * 4;
  const bool avalid = (m0 + ar) < n_rows;
  const bf16* aptr = Abase + (long)e * a_estride + (long)(m0 + ar) * a_ld + ac;
  const float* bptr = Bbase + (long)e * b_estride + nb * BN + tid;

  f32x4 acc[8];
  const f32x4 z = {0.f, 0.f, 0.f, 0.f};
  #pragma unroll
  for (int i = 0; i < 8; ++i) acc[i] = z;

  for (int k0 = 0; k0 < kdim; k0 += BK) {
    uint2 av = {0u, 0u};
    if (avalid) av = *(const uint2*)aptr;
    *(uint2*)(sm.A + ar * LDP + ac) = av;
    #pragma unroll
    for (int v = 0; v < 8; ++v) {
      float b0 = bptr[(long)(v * 4 + 0) * ldb];
      float b1 = bptr[(long)(v * 4 + 1) * ldb];
      float b2 = bptr[(long)(v * 4 + 2) * ldb];
      float b3 = bptr[(long)(v * 4 + 3) * ldb];
      bf16 __align__(8) tb[4] = {(bf16)b0, (bf16)b1, (bf16)b2, (bf16)b3};
      *(uint2*)(sm.Bt + tid * LDP + v * 4) = *(const uint2*)tb;
    }
    __syncthreads();
    bf16x8 af = *(const bf16x8*)(sm.A + (m_base + l16) * LDP + q * 8);
    #pragma unroll
    for (int nt = 0; nt < 8; ++nt) {
      bf16x8 bfv = *(const bf16x8*)(sm.Bt + (n_base + nt * 16 + l16) * LDP + q * 8);
      acc[nt] = __builtin_amdgcn_mfma_f32_16x16x32_bf16(af, bfv, acc[nt], 0, 0, 0);
    }
    __syncthreads();
    aptr += BK;
    bptr += (long)BK * ldb;
  }

  long ob = (long)e * out_estride + (long)(nb * BN + n_base + l16);
  #pragma unroll
  for (int nt = 0; nt < 8; ++nt)
    #pragma unroll
    for (int r = 0; r < 4; ++r) {
      int row = m0 + m_base + q * 4 + r;
      Out[ob + (long)row * out_ld + nt * 16] = (OutT)acc[nt][r];
    }
}

// ---------------------------------------------------------------- combine
__global__ __launch_bounds__(256) void combine(const float* __restrict__ tkw,
                                               const int* __restrict__ tki,
                                               const int* __restrict__ slot_a,
                                               const bf16* __restrict__ Y,
                                               float* __restrict__ out) {
  const int t = blockIdx.x, tid = threadIdx.x;
  long o = (long)t * H_DIM + tid * 4;
  float4 v = *(float4*)(out + o);  // shared-expert result already here
  float a0 = v.x, a1 = v.y, a2 = v.z, a3 = v.w;
  #pragma unroll
  for (int k = 0; k < KTOP; ++k) {
    int a = t * KTOP + k;
    int slot = slot_a[a];
    if (slot >= 0) {
      int e = tki[a];
      float w = tkw[a] * SCALE_F;
      const bf16* yr = Y + ((long)e * CAP + slot) * H_DIM + tid * 4;
      uint2 yv = *(const uint2*)yr;
      bf16 __align__(8) yb[4];
      *(uint2*)yb = yv;
      a0 += w * (float)yb[0];
      a1 += w * (float)yb[1];
      a2 += w * (float)yb[2];
      a3 += w * (float)yb[3];
    }
  }
  *(float4*)(out + o) = make_float4(a0, a1, a2, a3);
}

// ---------------------------------------------------------------- launch
extern "C" void kernel_launch(void* const* d_in, const int* in_sizes, int n_in,
                              void* d_out, int out_size, void* d_ws, size_t ws_size,
                              hipStream_t stream) {
  const float* x     = (const float*)d_in[0];
  const float* gw    = (const float*)d_in[1];
  const float* bias  = (const float*)d_in[2];
  const float* w_gu  = (const float*)d_in[3];
  const float* w_dn  = (const float*)d_in[4];
  const float* ws_gu = (const float*)d_in[5];
  const float* ws_dn = (const float*)d_in[6];
  float* out = (float*)d_out;
  char* ws = (char*)d_ws;

  // workspace layout (bytes)
  bf16* xbf     = (bf16*)(ws + 0);          // 2,097,152
  bf16* acts    = (bf16*)(ws + 2097152);    // 2,097,152  shared act [T][1024]
  bf16* actr    = (bf16*)(ws + 4194304);    // 16,777,216 routed act [E][CAP][512]
  bf16* Y       = (bf16*)(ws + 20971520);   // 33,554,432 routed out [E][CAP][1024]
  int*  tki     = (int*)(ws + 54525952);    // 24,576
  float* tkw    = (float*)(ws + 54550528);  // 24,576
  int*  rowlist = (int*)(ws + 54575104);    // 65,536
  int*  slot_a  = (int*)(ws + 54640640);    // 24,576
  int*  counts  = (int*)(ws + 54665216);    // 256   -> total ~54.7 MB

  cvt_bf16<<<dim3((T_DIM * H_DIM) / 1024), dim3(256), 0, stream>>>(x, xbf);
  router_topk<<<dim3(T_DIM), dim3(256), 0, stream>>>(x, gw, bias, tki, tkw);
  dispatch<<<dim3(E_NUM), dim3(64), 0, stream>>>(tki, rowlist, slot_a, counts);

  // routed gate_up + silu: grid (CAP/BM, I/128, E)
  gemm_gu<<<dim3(CAP / BM, I_DIM / 128, E_NUM), dim3(256), 0, stream>>>(
      xbf, H_DIM, rowlist, counts, 0,
      w_gu, 2 * I_DIM, (long)H_DIM * 2 * I_DIM, I_DIM,
      actr, I_DIM, (long)CAP * I_DIM, H_DIM);

  // shared gate_up + silu: I_s = 1024, gu width 2048
  gemm_gu<<<dim3(T_DIM / BM, 1024 / 128, 1), dim3(256), 0, stream>>>(
      xbf, H_DIM, nullptr, nullptr, T_DIM,
      ws_gu, 2048, 0, 1024,
      acts, 1024, 0, H_DIM);

  // routed down: [E]: act[CAP,512] @ w_down[512,1024] -> Y bf16
  gemm_down<bf16><<<dim3(CAP / BM, H_DIM / BN, E_NUM), dim3(256), 0, stream>>>(
      actr, (long)CAP * I_DIM, I_DIM, counts, 0,
      w_dn, (long)I_DIM * H_DIM, H_DIM,
      Y, (long)CAP * H_DIM, H_DIM, I_DIM);

  // shared down: acts[1024,1024] @ ws_down[1024,1024] -> out fp32 (full overwrite)
  gemm_down<float><<<dim3(T_DIM / BM, H_DIM / BN, 1), dim3(256), 0, stream>>>(
      acts, 0, 1024, nullptr, T_DIM,
      ws_dn, 0, H_DIM,
      out, 0, H_DIM, 1024);

  combine<<<dim3(T_DIM), dim3(256), 0, stream>>>(tkw, tki, slot_a, Y, out);
}

// Round 2
// 816.671 us; speedup vs baseline: 1.0972x; 1.0972x over previous
//
#include <hip/hip_runtime.h>
#include <math.h>

typedef __bf16 bf16;
typedef bf16 bf16x8 __attribute__((ext_vector_type(8)));
typedef float f32x4 __attribute__((ext_vector_type(4)));

#define T_DIM 1024
#define H_DIM 1024
#define E_NUM 64
#define I_DIM 512
#define KTOP 6
#define TKG 3
#define CAP 256
#define A_TOT (T_DIM * KTOP)
#define SCALE_F 2.5f

#define BM 32
#define BN 256
#define BK 32
#define LDP 40   // padded LDS k-stride (bf16): conflict-light ds_read_b128
#define GUP 260  // padded epilogue float stride

// ---------------------------------------------------------------- convert x -> bf16
__global__ __launch_bounds__(256) void cvt_bf16(const float* __restrict__ in,
                                                bf16* __restrict__ out) {
  int i = (blockIdx.x * 256 + threadIdx.x) * 4;
  float4 v = *(const float4*)(in + i);
  bf16 __align__(8) t[4] = {(bf16)v.x, (bf16)v.y, (bf16)v.z, (bf16)v.w};
  *(uint2*)(out + i) = *(const uint2*)t;
}

// ---------------------------------------------------------------- transpose+cvt: [R][C] fp32 -> [C][R] bf16 (batched over z)
__global__ __launch_bounds__(256) void transpose_cvt(const float* __restrict__ in,
                                                     bf16* __restrict__ out,
                                                     int R, int C) {
  __shared__ bf16 tile[64][68];
  const long bb = (long)blockIdx.z * R * C;
  in += bb;
  out += bb;
  const int r0 = blockIdx.x * 64, c0 = blockIdx.y * 64;
  const int tid = threadIdx.x;
  const int lr = tid >> 4;          // 0..15
  const int lc = (tid & 15) * 4;    // 0..60
  #pragma unroll
  for (int rr = 0; rr < 64; rr += 16) {
    float4 v = *(const float4*)(in + (long)(r0 + lr + rr) * C + c0 + lc);
    bf16 __align__(8) t4[4] = {(bf16)v.x, (bf16)v.y, (bf16)v.z, (bf16)v.w};
    *(uint2*)(&tile[lr + rr][lc]) = *(const uint2*)t4;
  }
  __syncthreads();
  const int orow = tid >> 3;        // 0..31
  const int oc = (tid & 7) * 8;
  #pragma unroll
  for (int p = 0; p < 64; p += 32) {
    bf16 __align__(16) t8[8];
    #pragma unroll
    for (int j = 0; j < 8; ++j) t8[j] = tile[oc + j][orow + p];
    *(uint4*)(out + (long)(c0 + orow + p) * R + r0 + oc) = *(const uint4*)t8;
  }
}

// ---------------------------------------------------------------- router + grouped top-k
__global__ __launch_bounds__(256) void router_topk(const float* __restrict__ x,
                                                   const float* __restrict__ gw,
                                                   const float* __restrict__ bias,
                                                   int* __restrict__ topk_id,
                                                   float* __restrict__ topk_w) {
  __shared__ float part[4][64];
  const int t = blockIdx.x;
  const int tid = threadIdx.x;
  const int wave = tid >> 6, lane = tid & 63;
  const float* xr = x + (long)t * H_DIM + wave * 256;
  float acc = 0.f;
  for (int h = 0; h < 256; h += 4) {
    float4 xv = *(const float4*)(xr + h);
    int hh = wave * 256 + h;
    acc += xv.x * gw[(hh + 0) * E_NUM + lane];
    acc += xv.y * gw[(hh + 1) * E_NUM + lane];
    acc += xv.z * gw[(hh + 2) * E_NUM + lane];
    acc += xv.w * gw[(hh + 3) * E_NUM + lane];
  }
  part[wave][lane] = acc;
  __syncthreads();
  if (wave != 0) return;
  acc = part[0][lane] + part[1][lane] + part[2][lane] + part[3][lane];

  float score = 1.f / (1.f + __expf(-acc));  // sigmoid (weights come from this)
  float sel = score + bias[lane];            // biased score (selection only)

  // top-2 within each group of 8 lanes
  float m1 = sel, m2 = -INFINITY;
  #pragma unroll
  for (int off = 1; off < 8; off <<= 1) {
    float o1 = __shfl_xor(m1, off);
    float o2 = __shfl_xor(m2, off);
    float mn = fminf(m1, o1);
    float alt = (m1 >= o1) ? m2 : o2;
    m1 = fmaxf(m1, o1);
    m2 = fmaxf(mn, alt);
  }
  float gscore = m1 + m2;

  // top-3 groups (argmax, lowest-index tiebreak)
  const int my_g = lane >> 3;
  unsigned gmask = 0;
  float gv = ((lane & 7) == 0) ? gscore : -INFINITY;
  for (int r = 0; r < TKG; ++r) {
    float v = gv;
    int idx = my_g;
    #pragma unroll
    for (int off = 1; off < 64; off <<= 1) {
      float ov = __shfl_xor(v, off);
      int oi = __shfl_xor(idx, off);
      if (ov > v || (ov == v && oi < idx)) { v = ov; idx = oi; }
    }
    gmask |= 1u << idx;
    if (my_g == idx) gv = -INFINITY;
  }

  // top-6 experts within selected groups
  float cand = ((gmask >> my_g) & 1u) ? sel : -INFINITY;
  float wk[KTOP];
  int ik[KTOP];
  float wsum = 0.f;
  for (int r = 0; r < KTOP; ++r) {
    float v = cand;
    int idx = lane;
    #pragma unroll
    for (int off = 1; off < 64; off <<= 1) {
      float ov = __shfl_xor(v, off);
      int oi = __shfl_xor(idx, off);
      if (ov > v || (ov == v && oi < idx)) { v = ov; idx = oi; }
    }
    float w = __shfl(score, idx);  // weight from UN-biased score
    wk[r] = w; ik[r] = idx; wsum += w;
    if (lane == idx) cand = -INFINITY;
  }
  if (lane == 0) {
    float inv = 1.f / wsum;
    #pragma unroll
    for (int r = 0; r < KTOP; ++r) {
      topk_id[t * KTOP + r] = ik[r];
      topk_w[t * KTOP + r] = wk[r] * inv;
    }
  }
}

// ---------------------------------------------------------------- dispatch (ordered compaction)
__global__ __launch_bounds__(64) void dispatch(const int* __restrict__ topk_id,
                                               int* __restrict__ rowlist,
                                               int* __restrict__ slot_a,
                                               int* __restrict__ counts) {
  __shared__ int ids[A_TOT];
  const int e = blockIdx.x, lane = threadIdx.x;
  for (int i = lane; i < A_TOT; i += 64) ids[i] = topk_id[i];
  __syncthreads();
  int base = 0;
  for (int a0 = 0; a0 < A_TOT; a0 += 64) {
    int a = a0 + lane;
    bool m = (ids[a] == e);
    unsigned long long bal = __ballot(m);
    if (m) {
      int pos = base + __popcll(bal & ((1ull << lane) - 1ull));
      slot_a[a] = (pos < CAP) ? pos : -1;
      if (pos < CAP) rowlist[e * CAP + pos] = a;
    }
    base += __popcll(bal);
  }
  if (lane == 0) counts[e] = (base < CAP) ? base : CAP;
}

// ---------------------------------------------------------------- gate_up GEMM + SiLU*mul (B^T bf16 [*, N, K])
struct __align__(16) SmemGU {
  union {
    struct { bf16 A[BM * LDP]; bf16 Bt[BN * LDP]; } k;
    float gu[BM * GUP];
  } u;
};

__global__ __launch_bounds__(256) void gemm_gu(
    const bf16* __restrict__ Abase, int a_ld,
    const int* __restrict__ rows, const int* __restrict__ counts, int n_rows_fixed,
    const bf16* __restrict__ BT, long b_estride, int u_off,
    bf16* __restrict__ actout, int act_ld, long act_estride, int kdim) {
  __shared__ SmemGU sm;
  const int e = blockIdx.z;
  const int n_rows = counts ? counts[e] : n_rows_fixed;
  const int m0 = blockIdx.x * BM;
  if (m0 >= n_rows) return;
  const int nb = blockIdx.y;
  const int tid = threadIdx.x;
  const int wave = tid >> 6, lane = tid & 63;
  const int q = lane >> 4, l16 = lane & 15;
  const int m_base = (wave & 1) * 16;
  const int n_base = (wave >> 1) * 128;

  // A staging: 32 rows x 32 k, 8 B/lane (gathered rows)
  const int ar = tid >> 3, ac = (tid & 7) * 4;
  const bool avalid = (m0 + ar) < n_rows;
  const bf16* aptr = Abase;
  if (avalid) {
    int grow = rows ? (rows[e * CAP + m0 + ar] / KTOP) : (m0 + ar);
    aptr = Abase + (long)grow * a_ld + ac;
  }
  // B staging: 4 BT-rows/lane, 16 B each, fully coalesced within a row
  const int koff = (tid & 3) * 8;
  const bf16* bptr[4];
  #pragma unroll
  for (int v = 0; v < 4; ++v) {
    int j = (tid >> 2) + v * 64;  // local n 0..255 (first 128 = gate, next = up)
    int ng = (j < 128) ? (nb * 128 + j) : (u_off + nb * 128 + j - 128);
    bptr[v] = BT + (long)e * b_estride + (long)ng * kdim + koff;
  }

  f32x4 acc[8];
  const f32x4 z = {0.f, 0.f, 0.f, 0.f};
  #pragma unroll
  for (int i = 0; i < 8; ++i) acc[i] = z;

  for (int k0 = 0; k0 < kdim; k0 += BK) {
    uint2 av = {0u, 0u};
    if (avalid) av = *(const uint2*)aptr;
    *(uint2*)(sm.u.k.A + ar * LDP + ac) = av;
    #pragma unroll
    for (int v = 0; v < 4; ++v) {
      int j = (tid >> 2) + v * 64;
      *(uint4*)(sm.u.k.Bt + j * LDP + koff) = *(const uint4*)bptr[v];
      bptr[v] += BK;
    }
    __syncthreads();
    bf16x8 af = *(const bf16x8*)(sm.u.k.A + (m_base + l16) * LDP + q * 8);
    #pragma unroll
    for (int nt = 0; nt < 8; ++nt) {
      bf16x8 bfv = *(const bf16x8*)(sm.u.k.Bt + (n_base + nt * 16 + l16) * LDP + q * 8);
      acc[nt] = __builtin_amdgcn_mfma_f32_16x16x32_bf16(af, bfv, acc[nt], 0, 0, 0);
    }
    __syncthreads();
    aptr += BK;
  }

  // D layout: col = lane&15, row = (lane>>4)*4 + reg  [m89-verified]
  #pragma unroll
  for (int nt = 0; nt < 8; ++nt)
    #pragma unroll
    for (int r = 0; r < 4; ++r)
      sm.u.gu[(m_base + q * 4 + r) * GUP + n_base + nt * 16 + l16] = acc[nt][r];
  __syncthreads();

  const int rr = tid >> 3;
  const int i0 = (tid & 7) * 16;
  bf16 __align__(16) tmp[16];
  #pragma unroll
  for (int j = 0; j < 16; ++j) {
    float g = sm.u.gu[rr * GUP + i0 + j];
    float uu = sm.u.gu[rr * GUP + 128 + i0 + j];
    float s = g / (1.f + __expf(-g));
    tmp[j] = (bf16)(s * uu);
  }
  long ob = (long)e * act_estride + (long)(m0 + rr) * act_ld + nb * 128 + i0;
  *(uint4*)(actout + ob) = *(const uint4*)tmp;
  *(uint4*)(actout + ob + 8) = *((const uint4*)tmp + 1);
}

// ---------------------------------------------------------------- down GEMM (B^T bf16)
struct __align__(16) SmemDN {
  union {
    struct { bf16 A[BM * LDP]; bf16 Bt[BN * LDP]; } k;
    float f[BM * GUP];
  } u;
};

template <typename OutT>
__global__ __launch_bounds__(256) void gemm_down(
    const bf16* __restrict__ Abase, long a_estride, int a_ld,
    const int* __restrict__ rows, const int* __restrict__ counts, int n_rows_fixed,
    const bf16* __restrict__ BT, long b_estride,
    OutT* __restrict__ Out, int out_ld, int kdim) {
  __shared__ SmemDN sm;
  const int e = blockIdx.z;
  const int n_rows = counts ? counts[e] : n_rows_fixed;
  const int m0 = blockIdx.x * BM;
  if (m0 >= n_rows) return;
  const int nb = blockIdx.y;
  const int tid = threadIdx.x;
  const int wave = tid >> 6, lane = tid & 63;
  const int q = lane >> 4, l16 = lane & 15;
  const int m_base = (wave & 1) * 16;
  const int n_base = (wave >> 1) * 128;

  const int ar = tid >> 3, ac = (tid & 7) * 4;
  const bool avalid = (m0 + ar) < n_rows;
  const bf16* aptr = Abase + (long)e * a_estride + (long)(m0 + ar) * a_ld + ac;
  const int koff = (tid & 3) * 8;
  const bf16* bptr[4];
  #pragma unroll
  for (int v = 0; v < 4; ++v) {
    int j = (tid >> 2) + v * 64;
    bptr[v] = BT + (long)e * b_estride + (long)(nb * BN + j) * kdim + koff;
  }

  f32x4 acc[8];
  const f32x4 z = {0.f, 0.f, 0.f, 0.f};
  #pragma unroll
  for (int i = 0; i < 8; ++i) acc[i] = z;

  for (int k0 = 0; k0 < kdim; k0 += BK) {
    uint2 av = {0u, 0u};
    if (avalid) av = *(const uint2*)aptr;
    *(uint2*)(sm.u.k.A + ar * LDP + ac) = av;
    #pragma unroll
    for (int v = 0; v < 4; ++v) {
      int j = (tid >> 2) + v * 64;
      *(uint4*)(sm.u.k.Bt + j * LDP + koff) = *(const uint4*)bptr[v];
      bptr[v] += BK;
    }
    __syncthreads();
    bf16x8 af = *(const bf16x8*)(sm.u.k.A + (m_base + l16) * LDP + q * 8);
    #pragma unroll
    for (int nt = 0; nt < 8; ++nt) {
      bf16x8 bfv = *(const bf16x8*)(sm.u.k.Bt + (n_base + nt * 16 + l16) * LDP + q * 8);
      acc[nt] = __builtin_amdgcn_mfma_f32_16x16x32_bf16(af, bfv, acc[nt], 0, 0, 0);
    }
    __syncthreads();
    aptr += BK;
  }

  // restage through LDS for vector global stores
  #pragma unroll
  for (int nt = 0; nt < 8; ++nt)
    #pragma unroll
    for (int r = 0; r < 4; ++r)
      sm.u.f[(m_base + q * 4 + r) * GUP + n_base + nt * 16 + l16] = acc[nt][r];
  __syncthreads();

  const int rr = tid >> 3;
  const int c0 = (tid & 7) * 32;
  if (m0 + rr < n_rows) {
    long orow = rows ? (long)rows[e * CAP + m0 + rr] : (long)(m0 + rr);
    OutT* op = Out + orow * out_ld + (long)nb * BN + c0;
    if constexpr (sizeof(OutT) == 2) {
      #pragma unroll
      for (int vv = 0; vv < 4; ++vv) {
        bf16 __align__(16) t8[8];
        #pragma unroll
        for (int j = 0; j < 8; ++j) t8[j] = (bf16)sm.u.f[rr * GUP + c0 + vv * 8 + j];
        *(uint4*)((bf16*)op + vv * 8) = *(const uint4*)t8;
      }
    } else {
      #pragma unroll
      for (int vv = 0; vv < 8; ++vv) {
        float4 fv = *(const float4*)(&sm.u.f[rr * GUP + c0 + vv * 4]);
        *(float4*)((float*)op + vv * 4) = fv;
      }
    }
  }
}

// ---------------------------------------------------------------- combine
__global__ __launch_bounds__(256) void combine(const float* __restrict__ tkw,
                                               const int* __restrict__ slot_a,
                                               const bf16* __restrict__ Ya,
                                               float* __restrict__ out) {
  const int t = blockIdx.x, tid = threadIdx.x;
  long o = (long)t * H_DIM + tid * 4;
  float4 v = *(float4*)(out + o);  // shared-expert result already here
  float a0 = v.x, a1 = v.y, a2 = v.z, a3 = v.w;
  #pragma unroll
  for (int k = 0; k < KTOP; ++k) {
    int a = t * KTOP + k;
    if (slot_a[a] >= 0) {
      float w = tkw[a] * SCALE_F;
      const bf16* yr = Ya + (long)a * H_DIM + tid * 4;
      uint2 yv = *(const uint2*)yr;
      bf16 __align__(8) yb[4];
      *(uint2*)yb = yv;
      a0 += w * (float)yb[0];
      a1 += w * (float)yb[1];
      a2 += w * (float)yb[2];
      a3 += w * (float)yb[3];
    }
  }
  *(float4*)(out + o) = make_float4(a0, a1, a2, a3);
}

// ---------------------------------------------------------------- launch
extern "C" void kernel_launch(void* const* d_in, const int* in_sizes, int n_in,
                              void* d_out, int out_size, void* d_ws, size_t ws_size,
                              hipStream_t stream) {
  const float* x     = (const float*)d_in[0];
  const float* gw    = (const float*)d_in[1];
  const float* bias  = (const float*)d_in[2];
  const float* w_gu  = (const float*)d_in[3];
  const float* w_dn  = (const float*)d_in[4];
  const float* ws_gu = (const float*)d_in[5];
  const float* ws_dn = (const float*)d_in[6];
  float* out = (float*)d_out;
  char* ws = (char*)d_ws;

  // workspace layout (bytes)
  bf16* xbf     = (bf16*)(ws + 0);           //  2,097,152
  bf16* acts    = (bf16*)(ws + 2097152);     //  2,097,152  shared act [T][1024]
  bf16* actr    = (bf16*)(ws + 4194304);     // 16,777,216  routed act [E][CAP][512]
  bf16* Ya      = (bf16*)(ws + 20971520);    // 12,582,912  routed out [A_TOT][1024]
  int*  tki     = (int*)(ws + 33554432);     // 24,576
  float* tkw    = (float*)(ws + 33579008);   // 24,576
  int*  rowlist = (int*)(ws + 33603584);     // 65,536
  int*  slot_a  = (int*)(ws + 33669120);     // 24,576
  int*  counts  = (int*)(ws + 33693696);     // 1,024
  bf16* wsguT   = (bf16*)(ws + 33694720);    //  4,194,304  [2048][1024]
  bf16* wsdnT   = (bf16*)(ws + 37889024);    //  2,097,152  [1024][1024]
  bf16* wguT    = (bf16*)(ws + 39986176);    // 134,217,728 [E][1024][1024]
  bf16* wdnT    = (bf16*)(ws + 39986176);    // aliases wguT (used after gate_up done)
  // total ~166 MB

  cvt_bf16<<<dim3((T_DIM * H_DIM) / 1024), dim3(256), 0, stream>>>(x, xbf);
  router_topk<<<dim3(T_DIM), dim3(256), 0, stream>>>(x, gw, bias, tki, tkw);
  dispatch<<<dim3(E_NUM), dim3(64), 0, stream>>>(tki, rowlist, slot_a, counts);

  // weight transposes (fp32 [R][C] -> bf16 [C][R])
  transpose_cvt<<<dim3(16, 16, 64), dim3(256), 0, stream>>>(w_gu, wguT, H_DIM, 2 * I_DIM);
  transpose_cvt<<<dim3(16, 32, 1), dim3(256), 0, stream>>>(ws_gu, wsguT, H_DIM, 2048);
  transpose_cvt<<<dim3(16, 16, 1), dim3(256), 0, stream>>>(ws_dn, wsdnT, 1024, H_DIM);

  // routed gate_up + silu
  gemm_gu<<<dim3(CAP / BM, I_DIM / 128, E_NUM), dim3(256), 0, stream>>>(
      xbf, H_DIM, rowlist, counts, 0,
      wguT, (long)(2 * I_DIM) * H_DIM, I_DIM,
      actr, I_DIM, (long)CAP * I_DIM, H_DIM);

  // shared gate_up + silu
  gemm_gu<<<dim3(T_DIM / BM, 2048 / 256, 1), dim3(256), 0, stream>>>(
      xbf, H_DIM, nullptr, nullptr, T_DIM,
      wsguT, 0, 1024,
      acts, 1024, 0, H_DIM);

  // w_dn transpose (aliases wguT region; stream-ordered after routed gate_up)
  transpose_cvt<<<dim3(8, 16, 64), dim3(256), 0, stream>>>(w_dn, wdnT, I_DIM, H_DIM);

  // routed down -> Ya (compacted by assignment index)
  gemm_down<bf16><<<dim3(CAP / BM, H_DIM / BN, E_NUM), dim3(256), 0, stream>>>(
      actr, (long)CAP * I_DIM, I_DIM, rowlist, counts, 0,
      wdnT, (long)H_DIM * I_DIM,
      Ya, H_DIM, I_DIM);

  // shared down -> out fp32 (full overwrite)
  gemm_down<float><<<dim3(T_DIM / BM, H_DIM / BN, 1), dim3(256), 0, stream>>>(
      acts, 0, 1024, nullptr, nullptr, T_DIM,
      wsdnT, 0,
      out, H_DIM, 1024);

  combine<<<dim3(T_DIM), dim3(256), 0, stream>>>(tkw, slot_a, Ya, out);
}

// Round 3
// 661.971 us; speedup vs baseline: 1.3536x; 1.2337x over previous
//
#include <hip/hip_runtime.h>
#include <math.h>

typedef __bf16 bf16;
typedef bf16 bf16x8 __attribute__((ext_vector_type(8)));
typedef float f32x4 __attribute__((ext_vector_type(4)));
typedef unsigned int u32;

#define T_DIM 1024
#define H_DIM 1024
#define E_NUM 64
#define I_DIM 512
#define KTOP 6
#define TKG 3
#define CAP 256
#define A_TOT (T_DIM * KTOP)
#define SCALE_F 2.5f

#define BMx 128
#define BNx 128
#define BKx 64  // k elems per tile (128 B per row, 8 chunks of 16 B)

// global_load_lds: per-lane global addr; LDS dest = wave-uniform base + lane*16.
typedef const u32 __attribute__((address_space(1)))* gas_t;
typedef u32 __attribute__((address_space(3)))* las_t;
__device__ __forceinline__ void gld16(const void* g, void* l) {
  __builtin_amdgcn_global_load_lds((gas_t)(unsigned long long)g,
                                   (las_t)(u32)(unsigned long long)l, 16, 0, 0);
}

// ---------------------------------------------------------------- convert x -> bf16
__global__ __launch_bounds__(256) void cvt_bf16(const float* __restrict__ in,
                                                bf16* __restrict__ out) {
  int i = (blockIdx.x * 256 + threadIdx.x) * 4;
  float4 v = *(const float4*)(in + i);
  bf16 __align__(8) t[4] = {(bf16)v.x, (bf16)v.y, (bf16)v.z, (bf16)v.w};
  *(uint2*)(out + i) = *(const uint2*)t;
}

// ---------------------------------------------------------------- transpose+cvt: [R][C] fp32 -> [C][R] bf16
__global__ __launch_bounds__(256) void transpose_cvt(const float* __restrict__ in,
                                                     bf16* __restrict__ out,
                                                     int R, int C) {
  __shared__ bf16 tile[64][68];
  const long bb = (long)blockIdx.z * R * C;
  in += bb;
  out += bb;
  const int r0 = blockIdx.x * 64, c0 = blockIdx.y * 64;
  const int tid = threadIdx.x;
  const int lr = tid >> 4;
  const int lc = (tid & 15) * 4;
  #pragma unroll
  for (int rr = 0; rr < 64; rr += 16) {
    float4 v = *(const float4*)(in + (long)(r0 + lr + rr) * C + c0 + lc);
    bf16 __align__(8) t4[4] = {(bf16)v.x, (bf16)v.y, (bf16)v.z, (bf16)v.w};
    *(uint2*)(&tile[lr + rr][lc]) = *(const uint2*)t4;
  }
  __syncthreads();
  const int orow = tid >> 3;
  const int oc = (tid & 7) * 8;
  #pragma unroll
  for (int p = 0; p < 64; p += 32) {
    bf16 __align__(16) t8[8];
    #pragma unroll
    for (int j = 0; j < 8; ++j) t8[j] = tile[oc + j][orow + p];
    *(uint4*)(out + (long)(c0 + orow + p) * R + r0 + oc) = *(const uint4*)t8;
  }
}

// ---------------------------------------------------------------- router + grouped top-k
__global__ __launch_bounds__(256) void router_topk(const float* __restrict__ x,
                                                   const float* __restrict__ gw,
                                                   const float* __restrict__ bias,
                                                   int* __restrict__ topk_id,
                                                   float* __restrict__ topk_w) {
  __shared__ float part[4][64];
  const int t = blockIdx.x;
  const int tid = threadIdx.x;
  const int wave = tid >> 6, lane = tid & 63;
  const float* xr = x + (long)t * H_DIM + wave * 256;
  float acc = 0.f;
  for (int h = 0; h < 256; h += 4) {
    float4 xv = *(const float4*)(xr + h);
    int hh = wave * 256 + h;
    acc += xv.x * gw[(hh + 0) * E_NUM + lane];
    acc += xv.y * gw[(hh + 1) * E_NUM + lane];
    acc += xv.z * gw[(hh + 2) * E_NUM + lane];
    acc += xv.w * gw[(hh + 3) * E_NUM + lane];
  }
  part[wave][lane] = acc;
  __syncthreads();
  if (wave != 0) return;
  acc = part[0][lane] + part[1][lane] + part[2][lane] + part[3][lane];

  float score = 1.f / (1.f + __expf(-acc));  // sigmoid (weights come from this)
  float sel = score + bias[lane];            // biased score (selection only)

  // top-2 within each group of 8 lanes
  float m1 = sel, m2 = -INFINITY;
  #pragma unroll
  for (int off = 1; off < 8; off <<= 1) {
    float o1 = __shfl_xor(m1, off);
    float o2 = __shfl_xor(m2, off);
    float mn = fminf(m1, o1);
    float alt = (m1 >= o1) ? m2 : o2;
    m1 = fmaxf(m1, o1);
    m2 = fmaxf(mn, alt);
  }
  float gscore = m1 + m2;

  // top-3 groups (argmax, lowest-index tiebreak)
  const int my_g = lane >> 3;
  unsigned gmask = 0;
  float gv = ((lane & 7) == 0) ? gscore : -INFINITY;
  for (int r = 0; r < TKG; ++r) {
    float v = gv;
    int idx = my_g;
    #pragma unroll
    for (int off = 1; off < 64; off <<= 1) {
      float ov = __shfl_xor(v, off);
      int oi = __shfl_xor(idx, off);
      if (ov > v || (ov == v && oi < idx)) { v = ov; idx = oi; }
    }
    gmask |= 1u << idx;
    if (my_g == idx) gv = -INFINITY;
  }

  // top-6 experts within selected groups
  float cand = ((gmask >> my_g) & 1u) ? sel : -INFINITY;
  float wk[KTOP];
  int ik[KTOP];
  float wsum = 0.f;
  for (int r = 0; r < KTOP; ++r) {
    float v = cand;
    int idx = lane;
    #pragma unroll
    for (int off = 1; off < 64; off <<= 1) {
      float ov = __shfl_xor(v, off);
      int oi = __shfl_xor(idx, off);
      if (ov > v || (ov == v && oi < idx)) { v = ov; idx = oi; }
    }
    float w = __shfl(score, idx);  // weight from UN-biased score
    wk[r] = w; ik[r] = idx; wsum += w;
    if (lane == idx) cand = -INFINITY;
  }
  if (lane == 0) {
    float inv = 1.f / wsum;
    #pragma unroll
    for (int r = 0; r < KTOP; ++r) {
      topk_id[t * KTOP + r] = ik[r];
      topk_w[t * KTOP + r] = wk[r] * inv;
    }
  }
}

// ---------------------------------------------------------------- dispatch (ordered compaction)
__global__ __launch_bounds__(64) void dispatch(const int* __restrict__ topk_id,
                                               int* __restrict__ rowlist,
                                               int* __restrict__ slot_a,
                                               int* __restrict__ counts) {
  __shared__ int ids[A_TOT];
  const int e = blockIdx.x, lane = threadIdx.x;
  for (int i = lane; i < A_TOT; i += 64) ids[i] = topk_id[i];
  __syncthreads();
  int base = 0;
  for (int a0 = 0; a0 < A_TOT; a0 += 64) {
    int a = a0 + lane;
    bool m = (ids[a] == e);
    unsigned long long bal = __ballot(m);
    if (m) {
      int pos = base + __popcll(bal & ((1ull << lane) - 1ull));
      slot_a[a] = (pos < CAP) ? pos : -1;
      if (pos < CAP) rowlist[e * CAP + pos] = a;
    }
    base += __popcll(bal);
  }
  if (lane == 0) counts[e] = (base < CAP) ? base : CAP;
}

// ================================================================ 128x128 MFMA GEMM, m97-style
// LDS [row][k] unpadded, BKx=64 (8 chunks/row of 16B), XOR swizzle chunk^(row&7).
// global_load_lds stages A (gathered rows OK: per-lane gptr) and B^T.

// ---------------------------------------------------------------- gate_up + fused SiLU*mul
// Block covers 64 gate cols + 64 up cols; each wave holds matching g/u pairs in regs.
__global__ __launch_bounds__(256) void gemm_gu(
    const bf16* __restrict__ X, int x_ld,
    const int* __restrict__ rows, const int* __restrict__ counts, int n_rows_fixed,
    const bf16* __restrict__ BT, long b_estride, int u_off,
    bf16* __restrict__ act, int act_ld, long act_estride, int kdim) {
  __shared__ union {
    struct { bf16 A[BMx * BKx]; bf16 B[BNx * BKx]; } st;  // 16 KB + 16 KB
    bf16 epi[BMx * 72];                                    // 18.4 KB repack
  } sm;
  const int e = blockIdx.z;
  const int n_rows = counts ? counts[e] : n_rows_fixed;
  const int m0 = blockIdx.x * BMx;
  if (m0 >= n_rows) return;
  const int nb = blockIdx.y;
  const int tid = threadIdx.x;
  const int w = tid >> 6, lane = tid & 63;
  const int q = lane >> 4, l16 = lane & 15;
  const int m_off = (w & 1) * 64;

  // staging geometry: per wave-inst j: rows w*32+j*8+(lane>>3), chunk (lane&7)^(lane>>3)
  const int srow = w * 32 + (lane >> 3);
  const int gchunk = (lane & 7) ^ (lane >> 3);
  const bf16* pA[4];
  const bf16* pB[4];
  #pragma unroll
  for (int j = 0; j < 4; ++j) {
    int tr = m0 + srow + j * 8;
    int grow;
    if (rows) grow = (tr < n_rows) ? (rows[e * CAP + tr] / KTOP) : 0;  // dead rows -> row 0 (finite garbage, masked later)
    else grow = tr;
    pA[j] = X + (long)grow * x_ld + gchunk * 8;
    int rB = srow + j * 8;
    int ng = (rB < 64) ? (nb * 64 + rB) : (u_off + nb * 64 + (rB - 64));
    pB[j] = BT + (long)e * b_estride + (long)ng * kdim + gchunk * 8;
  }
  bf16* ldsA = sm.st.A + w * 2048 + lane * 8;
  bf16* ldsB = sm.st.B + w * 2048 + lane * 8;

  f32x4 acc[4][4];
  #pragma unroll
  for (int i = 0; i < 4; ++i)
    #pragma unroll
    for (int j = 0; j < 4; ++j) acc[i][j] = (f32x4){0.f, 0.f, 0.f, 0.f};

  for (int k0 = 0; k0 < kdim; k0 += BKx) {
    #pragma unroll
    for (int j = 0; j < 4; ++j) {
      gld16(pA[j], ldsA + j * 512);
      gld16(pB[j], ldsB + j * 512);
      pA[j] += BKx;
      pB[j] += BKx;
    }
    __syncthreads();
    #pragma unroll
    for (int kh = 0; kh < 2; ++kh) {
      const int co = ((kh * 4 + q) ^ (l16 & 7)) * 8;
      bf16x8 a[4], b[4];
      #pragma unroll
      for (int i = 0; i < 4; ++i)
        a[i] = *(const bf16x8*)(sm.st.A + (m_off + i * 16 + l16) * BKx + co);
      #pragma unroll
      for (int j = 0; j < 4; ++j) {
        int nf = (j >> 1) * 64 + (w >> 1) * 32 + (j & 1) * 16;  // gate: j<2, up: j>=2 (+64)
        b[j] = *(const bf16x8*)(sm.st.B + (nf + l16) * BKx + co);
      }
      #pragma unroll
      for (int i = 0; i < 4; ++i)
        #pragma unroll
        for (int j = 0; j < 4; ++j)
          acc[i][j] = __builtin_amdgcn_mfma_f32_16x16x32_bf16(a[i], b[j], acc[i][j], 0, 0, 0);
    }
    __syncthreads();
  }

  // SiLU(g)*u in registers: g=acc[i][j], u=acc[i][j+2] (same lane/reg -> same row, col+64)
  const int c_base = (w >> 1) * 32;
  #pragma unroll
  for (int i = 0; i < 4; ++i)
    #pragma unroll
    for (int j = 0; j < 2; ++j)
      #pragma unroll
      for (int r = 0; r < 4; ++r) {
        float g = acc[i][j][r], uu = acc[i][j + 2][r];
        float s = g / (1.f + __expf(-g));
        sm.epi[(m_off + i * 16 + q * 4 + r) * 72 + c_base + j * 16 + l16] = (bf16)(s * uu);
      }
  __syncthreads();
  #pragma unroll
  for (int p = 0; p < 4; ++p) {
    int row = p * 32 + (tid >> 3);
    int c0 = (tid & 7) * 8;
    uint4 v = *(const uint4*)(sm.epi + row * 72 + c0);
    *(uint4*)(act + (long)e * act_estride + (long)(m0 + row) * act_ld + nb * 64 + c0) = v;
  }
}

// ---------------------------------------------------------------- down GEMM
template <typename OutT>
__global__ __launch_bounds__(256) void gemm_dn(
    const bf16* __restrict__ Abase, long a_estride, int a_ld,
    const int* __restrict__ rowsO, const int* __restrict__ counts, int n_rows_fixed,
    const bf16* __restrict__ BT, long b_estride,
    OutT* __restrict__ Out, int out_ld, int kdim) {
  __shared__ union {
    struct { bf16 A[BMx * BKx]; bf16 B[BNx * BKx]; } st;
    bf16 epi[BMx * 136];  // 34.8 KB bf16 repack
  } sm;
  const int e = blockIdx.z;
  const int n_rows = counts ? counts[e] : n_rows_fixed;
  const int m0 = blockIdx.x * BMx;
  if (m0 >= n_rows) return;
  const int nb = blockIdx.y;
  const int tid = threadIdx.x;
  const int w = tid >> 6, lane = tid & 63;
  const int q = lane >> 4, l16 = lane & 15;
  const int m_off = (w & 1) * 64;
  const int n_off = (w >> 1) * 64;

  const int srow = w * 32 + (lane >> 3);
  const int gchunk = (lane & 7) ^ (lane >> 3);
  const bf16* pA[4];
  const bf16* pB[4];
  #pragma unroll
  for (int j = 0; j < 4; ++j) {
    pA[j] = Abase + (long)e * a_estride + (long)(m0 + srow + j * 8) * a_ld + gchunk * 8;
    pB[j] = BT + (long)e * b_estride + (long)(nb * BNx + srow + j * 8) * kdim + gchunk * 8;
  }
  bf16* ldsA = sm.st.A + w * 2048 + lane * 8;
  bf16* ldsB = sm.st.B + w * 2048 + lane * 8;

  f32x4 acc[4][4];
  #pragma unroll
  for (int i = 0; i < 4; ++i)
    #pragma unroll
    for (int j = 0; j < 4; ++j) acc[i][j] = (f32x4){0.f, 0.f, 0.f, 0.f};

  for (int k0 = 0; k0 < kdim; k0 += BKx) {
    #pragma unroll
    for (int j = 0; j < 4; ++j) {
      gld16(pA[j], ldsA + j * 512);
      gld16(pB[j], ldsB + j * 512);
      pA[j] += BKx;
      pB[j] += BKx;
    }
    __syncthreads();
    #pragma unroll
    for (int kh = 0; kh < 2; ++kh) {
      const int co = ((kh * 4 + q) ^ (l16 & 7)) * 8;
      bf16x8 a[4], b[4];
      #pragma unroll
      for (int i = 0; i < 4; ++i)
        a[i] = *(const bf16x8*)(sm.st.A + (m_off + i * 16 + l16) * BKx + co);
      #pragma unroll
      for (int j = 0; j < 4; ++j)
        b[j] = *(const bf16x8*)(sm.st.B + (n_off + j * 16 + l16) * BKx + co);
      #pragma unroll
      for (int i = 0; i < 4; ++i)
        #pragma unroll
        for (int j = 0; j < 4; ++j)
          acc[i][j] = __builtin_amdgcn_mfma_f32_16x16x32_bf16(a[i], b[j], acc[i][j], 0, 0, 0);
    }
    __syncthreads();
  }

  if constexpr (sizeof(OutT) == 4) {
    // fp32 direct store (quad = 64 B contiguous per (i,j,r))
    #pragma unroll
    for (int i = 0; i < 4; ++i)
      #pragma unroll
      for (int j = 0; j < 4; ++j)
        #pragma unroll
        for (int r = 0; r < 4; ++r) {
          int row = m0 + m_off + i * 16 + q * 4 + r;
          Out[(long)row * out_ld + nb * BNx + n_off + j * 16 + l16] = acc[i][j][r];
        }
  } else {
    // bf16 repack via LDS, gathered output rows
    #pragma unroll
    for (int i = 0; i < 4; ++i)
      #pragma unroll
      for (int j = 0; j < 4; ++j)
        #pragma unroll
        for (int r = 0; r < 4; ++r)
          sm.epi[(m_off + i * 16 + q * 4 + r) * 136 + n_off + j * 16 + l16] = (bf16)acc[i][j][r];
    __syncthreads();
    #pragma unroll
    for (int p = 0; p < 8; ++p) {
      int row = p * 16 + (tid >> 4);
      int c0 = (tid & 15) * 8;
      if (m0 + row < n_rows) {
        long orow = rowsO ? (long)rowsO[e * CAP + m0 + row] : (long)(m0 + row);
        *(uint4*)((bf16*)Out + orow * out_ld + nb * BNx + c0) =
            *(const uint4*)(sm.epi + row * 136 + c0);
      }
    }
  }
}

// ---------------------------------------------------------------- combine
__global__ __launch_bounds__(256) void combine(const float* __restrict__ tkw,
                                               const int* __restrict__ slot_a,
                                               const bf16* __restrict__ Ya,
                                               float* __restrict__ out) {
  const int t = blockIdx.x, tid = threadIdx.x;
  long o = (long)t * H_DIM + tid * 4;
  float4 v = *(float4*)(out + o);  // shared-expert result already here
  float a0 = v.x, a1 = v.y, a2 = v.z, a3 = v.w;
  #pragma unroll
  for (int k = 0; k < KTOP; ++k) {
    int a = t * KTOP + k;
    if (slot_a[a] >= 0) {
      float w = tkw[a] * SCALE_F;
      const bf16* yr = Ya + (long)a * H_DIM + tid * 4;
      uint2 yv = *(const uint2*)yr;
      bf16 __align__(8) yb[4];
      *(uint2*)yb = yv;
      a0 += w * (float)yb[0];
      a1 += w * (float)yb[1];
      a2 += w * (float)yb[2];
      a3 += w * (float)yb[3];
    }
  }
  *(float4*)(out + o) = make_float4(a0, a1, a2, a3);
}

// ---------------------------------------------------------------- launch
extern "C" void kernel_launch(void* const* d_in, const int* in_sizes, int n_in,
                              void* d_out, int out_size, void* d_ws, size_t ws_size,
                              hipStream_t stream) {
  const float* x     = (const float*)d_in[0];
  const float* gw    = (const float*)d_in[1];
  const float* bias  = (const float*)d_in[2];
  const float* w_gu  = (const float*)d_in[3];
  const float* w_dn  = (const float*)d_in[4];
  const float* ws_gu = (const float*)d_in[5];
  const float* ws_dn = (const float*)d_in[6];
  float* out = (float*)d_out;
  char* ws = (char*)d_ws;

  // workspace layout (bytes)
  bf16* xbf     = (bf16*)(ws + 0);           //  2,097,152
  bf16* acts    = (bf16*)(ws + 2097152);     //  2,097,152  shared act [T][1024]
  bf16* actr    = (bf16*)(ws + 4194304);     // 16,777,216  routed act [E][CAP][512]
  bf16* Ya      = (bf16*)(ws + 20971520);    // 12,582,912  routed out [A_TOT][1024]
  int*  tki     = (int*)(ws + 33554432);     // 24,576
  float* tkw    = (float*)(ws + 33579008);   // 24,576
  int*  rowlist = (int*)(ws + 33603584);     // 65,536
  int*  slot_a  = (int*)(ws + 33669120);     // 24,576
  int*  counts  = (int*)(ws + 33693696);     // 1,024
  bf16* wsguT   = (bf16*)(ws + 33694720);    //  4,194,304  [2048][1024]
  bf16* wsdnT   = (bf16*)(ws + 37889024);    //  2,097,152  [1024][1024]
  bf16* wguT    = (bf16*)(ws + 39986176);    // 134,217,728 [E][1024][1024]
  bf16* wdnT    = (bf16*)(ws + 39986176);    // aliases wguT (used after gate_up done)

  cvt_bf16<<<dim3((T_DIM * H_DIM) / 1024), dim3(256), 0, stream>>>(x, xbf);
  router_topk<<<dim3(T_DIM), dim3(256), 0, stream>>>(x, gw, bias, tki, tkw);
  dispatch<<<dim3(E_NUM), dim3(64), 0, stream>>>(tki, rowlist, slot_a, counts);

  // weight transposes (fp32 [R][C] -> bf16 [C][R])
  transpose_cvt<<<dim3(16, 16, 64), dim3(256), 0, stream>>>(w_gu, wguT, H_DIM, 2 * I_DIM);
  transpose_cvt<<<dim3(16, 32, 1), dim3(256), 0, stream>>>(ws_gu, wsguT, H_DIM, 2048);
  transpose_cvt<<<dim3(16, 16, 1), dim3(256), 0, stream>>>(ws_dn, wsdnT, 1024, H_DIM);

  // routed gate_up + silu: n-tiles = I/64
  gemm_gu<<<dim3(CAP / BMx, I_DIM / 64, E_NUM), dim3(256), 0, stream>>>(
      xbf, H_DIM, rowlist, counts, 0,
      wguT, (long)(2 * I_DIM) * H_DIM, I_DIM,
      actr, I_DIM, (long)CAP * I_DIM, H_DIM);

  // shared gate_up + silu: width 2048, u_off 1024
  gemm_gu<<<dim3(T_DIM / BMx, 1024 / 64, 1), dim3(256), 0, stream>>>(
      xbf, H_DIM, nullptr, nullptr, T_DIM,
      wsguT, 0, 1024,
      acts, 1024, 0, H_DIM);

  // w_dn transpose (aliases wguT region; stream-ordered after routed gate_up)
  transpose_cvt<<<dim3(8, 16, 64), dim3(256), 0, stream>>>(w_dn, wdnT, I_DIM, H_DIM);

  // routed down -> Ya (gathered by assignment index)
  gemm_dn<bf16><<<dim3(CAP / BMx, H_DIM / BNx, E_NUM), dim3(256), 0, stream>>>(
      actr, (long)CAP * I_DIM, I_DIM, rowlist, counts, 0,
      wdnT, (long)H_DIM * I_DIM,
      (bf16*)Ya, H_DIM, I_DIM);

  // shared down -> out fp32 (full overwrite)
  gemm_dn<float><<<dim3(T_DIM / BMx, H_DIM / BNx, 1), dim3(256), 0, stream>>>(
      acts, 0, 1024, nullptr, nullptr, T_DIM,
      wsdnT, 0,
      out, H_DIM, 1024);

  combine<<<dim3(T_DIM), dim3(256), 0, stream>>>(tkw, slot_a, Ya, out);
}

// Round 4
// 595.853 us; speedup vs baseline: 1.5038x; 1.1110x over previous
//
#include <hip/hip_runtime.h>
#include <math.h>

typedef __bf16 bf16;
typedef bf16 bf16x8 __attribute__((ext_vector_type(8)));
typedef float f32x4 __attribute__((ext_vector_type(4)));
typedef unsigned int u32;

#define T_DIM 1024
#define H_DIM 1024
#define E_NUM 64
#define I_DIM 512
#define KTOP 6
#define TKG 3
#define CAP 256
#define A_TOT (T_DIM * KTOP)
#define SCALE_F 2.5f

#define BMx 128
#define BNx 128
#define BKx 64  // k elems per tile

// global_load_lds: per-lane global addr; LDS dest = wave-uniform base + lane*16.
typedef const u32 __attribute__((address_space(1)))* gas_t;
typedef u32 __attribute__((address_space(3)))* las_t;
__device__ __forceinline__ void gld16(const void* g, void* l) {
  __builtin_amdgcn_global_load_lds((gas_t)(unsigned long long)g,
                                   (las_t)(u32)(unsigned long long)l, 16, 0, 0);
}

// B-LDS swizzle: chunk stored at (kc ^ s(n)); s gives conflict-free b128 writes
// (8 bank-groups across half-wave) and 2-way (free) b128 frag reads.
__device__ __forceinline__ int bswz(int n) {
  return ((n >> 2) ^ ((n & 3) << 1)) & 7;
}

// ---------------------------------------------------------------- convert x -> bf16
__global__ __launch_bounds__(256) void cvt_bf16(const float* __restrict__ in,
                                                bf16* __restrict__ out) {
  int i = (blockIdx.x * 256 + threadIdx.x) * 4;
  float4 v = *(const float4*)(in + i);
  bf16 __align__(8) t[4] = {(bf16)v.x, (bf16)v.y, (bf16)v.z, (bf16)v.w};
  *(uint2*)(out + i) = *(const uint2*)t;
}

// ---------------------------------------------------------------- router + grouped top-k
__global__ __launch_bounds__(256) void router_topk(const float* __restrict__ x,
                                                   const float* __restrict__ gw,
                                                   const float* __restrict__ bias,
                                                   int* __restrict__ topk_id,
                                                   float* __restrict__ topk_w) {
  __shared__ float part[4][64];
  const int t = blockIdx.x;
  const int tid = threadIdx.x;
  const int wave = tid >> 6, lane = tid & 63;
  const float* xr = x + (long)t * H_DIM + wave * 256;
  float acc = 0.f;
  for (int h = 0; h < 256; h += 4) {
    float4 xv = *(const float4*)(xr + h);
    int hh = wave * 256 + h;
    acc += xv.x * gw[(hh + 0) * E_NUM + lane];
    acc += xv.y * gw[(hh + 1) * E_NUM + lane];
    acc += xv.z * gw[(hh + 2) * E_NUM + lane];
    acc += xv.w * gw[(hh + 3) * E_NUM + lane];
  }
  part[wave][lane] = acc;
  __syncthreads();
  if (wave != 0) return;
  acc = part[0][lane] + part[1][lane] + part[2][lane] + part[3][lane];

  float score = 1.f / (1.f + __expf(-acc));  // sigmoid (weights come from this)
  float sel = score + bias[lane];            // biased score (selection only)

  // top-2 within each group of 8 lanes
  float m1 = sel, m2 = -INFINITY;
  #pragma unroll
  for (int off = 1; off < 8; off <<= 1) {
    float o1 = __shfl_xor(m1, off);
    float o2 = __shfl_xor(m2, off);
    float mn = fminf(m1, o1);
    float alt = (m1 >= o1) ? m2 : o2;
    m1 = fmaxf(m1, o1);
    m2 = fmaxf(mn, alt);
  }
  float gscore = m1 + m2;

  // top-3 groups (argmax, lowest-index tiebreak)
  const int my_g = lane >> 3;
  unsigned gmask = 0;
  float gv = ((lane & 7) == 0) ? gscore : -INFINITY;
  for (int r = 0; r < TKG; ++r) {
    float v = gv;
    int idx = my_g;
    #pragma unroll
    for (int off = 1; off < 64; off <<= 1) {
      float ov = __shfl_xor(v, off);
      int oi = __shfl_xor(idx, off);
      if (ov > v || (ov == v && oi < idx)) { v = ov; idx = oi; }
    }
    gmask |= 1u << idx;
    if (my_g == idx) gv = -INFINITY;
  }

  // top-6 experts within selected groups
  float cand = ((gmask >> my_g) & 1u) ? sel : -INFINITY;
  float wk[KTOP];
  int ik[KTOP];
  float wsum = 0.f;
  for (int r = 0; r < KTOP; ++r) {
    float v = cand;
    int idx = lane;
    #pragma unroll
    for (int off = 1; off < 64; off <<= 1) {
      float ov = __shfl_xor(v, off);
      int oi = __shfl_xor(idx, off);
      if (ov > v || (ov == v && oi < idx)) { v = ov; idx = oi; }
    }
    float w = __shfl(score, idx);  // weight from UN-biased score
    wk[r] = w; ik[r] = idx; wsum += w;
    if (lane == idx) cand = -INFINITY;
  }
  if (lane == 0) {
    float inv = 1.f / wsum;
    #pragma unroll
    for (int r = 0; r < KTOP; ++r) {
      topk_id[t * KTOP + r] = ik[r];
      topk_w[t * KTOP + r] = wk[r] * inv;
    }
  }
}

// ---------------------------------------------------------------- dispatch (ordered compaction)
__global__ __launch_bounds__(64) void dispatch(const int* __restrict__ topk_id,
                                               int* __restrict__ rowlist,
                                               int* __restrict__ slot_a,
                                               int* __restrict__ counts) {
  __shared__ int ids[A_TOT];
  const int e = blockIdx.x, lane = threadIdx.x;
  for (int i = lane; i < A_TOT; i += 64) ids[i] = topk_id[i];
  __syncthreads();
  int base = 0;
  for (int a0 = 0; a0 < A_TOT; a0 += 64) {
    int a = a0 + lane;
    bool m = (ids[a] == e);
    unsigned long long bal = __ballot(m);
    if (m) {
      int pos = base + __popcll(bal & ((1ull << lane) - 1ull));
      slot_a[a] = (pos < CAP) ? pos : -1;
      if (pos < CAP) rowlist[e * CAP + pos] = a;
    }
    base += __popcll(bal);
  }
  if (lane == 0) counts[e] = (base < CAP) ? base : CAP;
}

// ================================================================ 128x128 MFMA GEMM
// A: bf16 rows (optionally gathered) staged via global_load_lds, XOR swizzle row&7.
// B: fp32 [K][N] weight, fused transpose+cvt: regs -> bf16 LDS [n][k], swizzle bswz(n).

// ---------------------------------------------------------------- gate_up + fused SiLU*mul
__global__ __launch_bounds__(256) void gemm_gu(
    const bf16* __restrict__ X, int x_ld,
    const int* __restrict__ rows, const int* __restrict__ counts, int n_rows_fixed,
    const float* __restrict__ W, long w_estride, int ldb, int u_off,
    bf16* __restrict__ act, int act_ld, long act_estride, int kdim) {
  __shared__ union {
    struct { bf16 A[BMx * BKx]; bf16 B[BNx * BKx]; } st;  // 16 KB + 16 KB
    bf16 epi[BMx * 72];                                    // 18.4 KB repack
  } sm;
  const int e = blockIdx.z;
  const int n_rows = counts ? counts[e] : n_rows_fixed;
  const int m0 = blockIdx.x * BMx;
  if (m0 >= n_rows) return;
  const int nb = blockIdx.y;
  const int tid = threadIdx.x;
  const int w = tid >> 6, lane = tid & 63;
  const int q = lane >> 4, l16 = lane & 15;
  const int m_off = (w & 1) * 64;

  // ---- A staging geometry (global_load_lds)
  const int srow = w * 32 + (lane >> 3);
  const int gchunk = (lane & 7) ^ (lane >> 3);
  const bf16* pA[4];
  #pragma unroll
  for (int j = 0; j < 4; ++j) {
    int tr = m0 + srow + j * 8;
    int grow;
    if (rows) grow = (tr < n_rows) ? (rows[e * CAP + tr] / KTOP) : 0;
    else grow = tr;
    pA[j] = X + (long)grow * x_ld + gchunk * 8;
  }
  bf16* ldsA = sm.st.A + w * 2048 + lane * 8;

  // ---- B staging geometry (fp32 -> regs -> bf16 LDS transposed)
  const int kc = tid >> 5;          // 0..7 (k-chunk of 8 rows)
  const int n0 = (tid & 31) * 4;    // local col base 0..124
  const int gcol = (n0 < 64) ? (nb * 64 + n0) : (u_off + nb * 64 + (n0 - 64));
  const float* bcol = W + (long)e * w_estride + (long)kc * 8 * ldb + gcol;
  float4 bv[8];
  #pragma unroll
  for (int r = 0; r < 8; ++r) bv[r] = *(const float4*)(bcol + (long)r * ldb);

  f32x4 acc[4][4];
  #pragma unroll
  for (int i = 0; i < 4; ++i)
    #pragma unroll
    for (int j = 0; j < 4; ++j) acc[i][j] = (f32x4){0.f, 0.f, 0.f, 0.f};

  for (int k0 = 0; k0 < kdim; k0 += BKx) {
    #pragma unroll
    for (int j = 0; j < 4; ++j) {
      gld16(pA[j], ldsA + j * 512);
      pA[j] += BKx;
    }
    // convert + transposed LDS write (4x ds_write_b128)
    #pragma unroll
    for (int j = 0; j < 4; ++j) {
      bf16 __align__(16) t8[8];
      #pragma unroll
      for (int r = 0; r < 8; ++r) t8[r] = (bf16)((const float*)&bv[r])[j];
      int n = n0 + j;
      *(uint4*)(sm.st.B + n * BKx + ((kc ^ bswz(n)) * 8)) = *(const uint4*)t8;
    }
    // prefetch next B tile into regs (overlaps barrier + MFMA)
    if (k0 + BKx < kdim) {
      const float* bnext = bcol + (long)(k0 + BKx) * ldb;
      #pragma unroll
      for (int r = 0; r < 8; ++r) bv[r] = *(const float4*)(bnext + (long)r * ldb);
    }
    __syncthreads();
    #pragma unroll
    for (int kh = 0; kh < 2; ++kh) {
      bf16x8 a[4], b[4];
      const int co = ((kh * 4 + q) ^ (l16 & 7)) * 8;
      #pragma unroll
      for (int i = 0; i < 4; ++i)
        a[i] = *(const bf16x8*)(sm.st.A + (m_off + i * 16 + l16) * BKx + co);
      #pragma unroll
      for (int j = 0; j < 4; ++j) {
        int nf = (j >> 1) * 64 + (w >> 1) * 32 + (j & 1) * 16;  // gate: j<2; up: j>=2
        int n = nf + l16;
        b[j] = *(const bf16x8*)(sm.st.B + n * BKx + (((kh * 4 + q) ^ bswz(n)) * 8));
      }
      #pragma unroll
      for (int i = 0; i < 4; ++i)
        #pragma unroll
        for (int j = 0; j < 4; ++j)
          acc[i][j] = __builtin_amdgcn_mfma_f32_16x16x32_bf16(a[i], b[j], acc[i][j], 0, 0, 0);
    }
    __syncthreads();
  }

  // SiLU(g)*u in registers: g=acc[i][j], u=acc[i][j+2] (same row, col+64)
  const int c_base = (w >> 1) * 32;
  #pragma unroll
  for (int i = 0; i < 4; ++i)
    #pragma unroll
    for (int j = 0; j < 2; ++j)
      #pragma unroll
      for (int r = 0; r < 4; ++r) {
        float g = acc[i][j][r], uu = acc[i][j + 2][r];
        float s = g / (1.f + __expf(-g));
        sm.epi[(m_off + i * 16 + q * 4 + r) * 72 + c_base + j * 16 + l16] = (bf16)(s * uu);
      }
  __syncthreads();
  #pragma unroll
  for (int p = 0; p < 4; ++p) {
    int row = p * 32 + (tid >> 3);
    int c0 = (tid & 7) * 8;
    uint4 v = *(const uint4*)(sm.epi + row * 72 + c0);
    *(uint4*)(act + (long)e * act_estride + (long)(m0 + row) * act_ld + nb * 64 + c0) = v;
  }
}

// ---------------------------------------------------------------- down GEMM
template <typename OutT>
__global__ __launch_bounds__(256) void gemm_dn(
    const bf16* __restrict__ Abase, long a_estride, int a_ld,
    const int* __restrict__ rowsO, const int* __restrict__ counts, int n_rows_fixed,
    const float* __restrict__ W, long w_estride, int ldb,
    OutT* __restrict__ Out, int out_ld, int kdim) {
  __shared__ union {
    struct { bf16 A[BMx * BKx]; bf16 B[BNx * BKx]; } st;
    bf16 epi[BMx * 136];  // 34.8 KB bf16 repack
  } sm;
  const int e = blockIdx.z;
  const int n_rows = counts ? counts[e] : n_rows_fixed;
  const int m0 = blockIdx.x * BMx;
  if (m0 >= n_rows) return;
  const int nb = blockIdx.y;
  const int tid = threadIdx.x;
  const int w = tid >> 6, lane = tid & 63;
  const int q = lane >> 4, l16 = lane & 15;
  const int m_off = (w & 1) * 64;
  const int n_off = (w >> 1) * 64;

  const int srow = w * 32 + (lane >> 3);
  const int gchunk = (lane & 7) ^ (lane >> 3);
  const bf16* pA[4];
  #pragma unroll
  for (int j = 0; j < 4; ++j)
    pA[j] = Abase + (long)e * a_estride + (long)(m0 + srow + j * 8) * a_ld + gchunk * 8;
  bf16* ldsA = sm.st.A + w * 2048 + lane * 8;

  const int kc = tid >> 5;
  const int n0 = (tid & 31) * 4;
  const float* bcol = W + (long)e * w_estride + (long)kc * 8 * ldb + nb * BNx + n0;
  float4 bv[8];
  #pragma unroll
  for (int r = 0; r < 8; ++r) bv[r] = *(const float4*)(bcol + (long)r * ldb);

  f32x4 acc[4][4];
  #pragma unroll
  for (int i = 0; i < 4; ++i)
    #pragma unroll
    for (int j = 0; j < 4; ++j) acc[i][j] = (f32x4){0.f, 0.f, 0.f, 0.f};

  for (int k0 = 0; k0 < kdim; k0 += BKx) {
    #pragma unroll
    for (int j = 0; j < 4; ++j) {
      gld16(pA[j], ldsA + j * 512);
      pA[j] += BKx;
    }
    #pragma unroll
    for (int j = 0; j < 4; ++j) {
      bf16 __align__(16) t8[8];
      #pragma unroll
      for (int r = 0; r < 8; ++r) t8[r] = (bf16)((const float*)&bv[r])[j];
      int n = n0 + j;
      *(uint4*)(sm.st.B + n * BKx + ((kc ^ bswz(n)) * 8)) = *(const uint4*)t8;
    }
    if (k0 + BKx < kdim) {
      const float* bnext = bcol + (long)(k0 + BKx) * ldb;
      #pragma unroll
      for (int r = 0; r < 8; ++r) bv[r] = *(const float4*)(bnext + (long)r * ldb);
    }
    __syncthreads();
    #pragma unroll
    for (int kh = 0; kh < 2; ++kh) {
      bf16x8 a[4], b[4];
      const int co = ((kh * 4 + q) ^ (l16 & 7)) * 8;
      #pragma unroll
      for (int i = 0; i < 4; ++i)
        a[i] = *(const bf16x8*)(sm.st.A + (m_off + i * 16 + l16) * BKx + co);
      #pragma unroll
      for (int j = 0; j < 4; ++j) {
        int n = n_off + j * 16 + l16;
        b[j] = *(const bf16x8*)(sm.st.B + n * BKx + (((kh * 4 + q) ^ bswz(n)) * 8));
      }
      #pragma unroll
      for (int i = 0; i < 4; ++i)
        #pragma unroll
        for (int j = 0; j < 4; ++j)
          acc[i][j] = __builtin_amdgcn_mfma_f32_16x16x32_bf16(a[i], b[j], acc[i][j], 0, 0, 0);
    }
    __syncthreads();
  }

  if constexpr (sizeof(OutT) == 4) {
    #pragma unroll
    for (int i = 0; i < 4; ++i)
      #pragma unroll
      for (int j = 0; j < 4; ++j)
        #pragma unroll
        for (int r = 0; r < 4; ++r) {
          int row = m0 + m_off + i * 16 + q * 4 + r;
          Out[(long)row * out_ld + nb * BNx + n_off + j * 16 + l16] = acc[i][j][r];
        }
  } else {
    #pragma unroll
    for (int i = 0; i < 4; ++i)
      #pragma unroll
      for (int j = 0; j < 4; ++j)
        #pragma unroll
        for (int r = 0; r < 4; ++r)
          sm.epi[(m_off + i * 16 + q * 4 + r) * 136 + n_off + j * 16 + l16] = (bf16)acc[i][j][r];
    __syncthreads();
    #pragma unroll
    for (int p = 0; p < 8; ++p) {
      int row = p * 16 + (tid >> 4);
      int c0 = (tid & 15) * 8;
      if (m0 + row < n_rows) {
        long orow = rowsO ? (long)rowsO[e * CAP + m0 + row] : (long)(m0 + row);
        *(uint4*)((bf16*)Out + orow * out_ld + nb * BNx + c0) =
            *(const uint4*)(sm.epi + row * 136 + c0);
      }
    }
  }
}

// ---------------------------------------------------------------- combine
__global__ __launch_bounds__(256) void combine(const float* __restrict__ tkw,
                                               const int* __restrict__ slot_a,
                                               const bf16* __restrict__ Ya,
                                               float* __restrict__ out) {
  const int t = blockIdx.x, tid = threadIdx.x;
  long o = (long)t * H_DIM + tid * 4;
  float4 v = *(float4*)(out + o);  // shared-expert result already here
  float a0 = v.x, a1 = v.y, a2 = v.z, a3 = v.w;
  #pragma unroll
  for (int k = 0; k < KTOP; ++k) {
    int a = t * KTOP + k;
    if (slot_a[a] >= 0) {
      float w = tkw[a] * SCALE_F;
      const bf16* yr = Ya + (long)a * H_DIM + tid * 4;
      uint2 yv = *(const uint2*)yr;
      bf16 __align__(8) yb[4];
      *(uint2*)yb = yv;
      a0 += w * (float)yb[0];
      a1 += w * (float)yb[1];
      a2 += w * (float)yb[2];
      a3 += w * (float)yb[3];
    }
  }
  *(float4*)(out + o) = make_float4(a0, a1, a2, a3);
}

// ---------------------------------------------------------------- launch
extern "C" void kernel_launch(void* const* d_in, const int* in_sizes, int n_in,
                              void* d_out, int out_size, void* d_ws, size_t ws_size,
                              hipStream_t stream) {
  const float* x     = (const float*)d_in[0];
  const float* gw    = (const float*)d_in[1];
  const float* bias  = (const float*)d_in[2];
  const float* w_gu  = (const float*)d_in[3];
  const float* w_dn  = (const float*)d_in[4];
  const float* ws_gu = (const float*)d_in[5];
  const float* ws_dn = (const float*)d_in[6];
  float* out = (float*)d_out;
  char* ws = (char*)d_ws;

  // workspace layout (bytes), total ~34 MB
  bf16* xbf     = (bf16*)(ws + 0);           //  2,097,152
  bf16* acts    = (bf16*)(ws + 2097152);     //  2,097,152  shared act [T][1024]
  bf16* actr    = (bf16*)(ws + 4194304);     // 16,777,216  routed act [E][CAP][512]
  bf16* Ya      = (bf16*)(ws + 20971520);    // 12,582,912  routed out [A_TOT][1024]
  int*  tki     = (int*)(ws + 33554432);     // 24,576
  float* tkw    = (float*)(ws + 33579008);   // 24,576
  int*  rowlist = (int*)(ws + 33603584);     // 65,536
  int*  slot_a  = (int*)(ws + 33669120);     // 24,576
  int*  counts  = (int*)(ws + 33693696);     // 1,024

  cvt_bf16<<<dim3((T_DIM * H_DIM) / 1024), dim3(256), 0, stream>>>(x, xbf);
  router_topk<<<dim3(T_DIM), dim3(256), 0, stream>>>(x, gw, bias, tki, tkw);
  dispatch<<<dim3(E_NUM), dim3(64), 0, stream>>>(tki, rowlist, slot_a, counts);

  // routed gate_up + silu: B = w_gu [e][1024][1024] fp32, gate cols 0..511, up 512..1023
  gemm_gu<<<dim3(CAP / BMx, I_DIM / 64, E_NUM), dim3(256), 0, stream>>>(
      xbf, H_DIM, rowlist, counts, 0,
      w_gu, (long)H_DIM * 2 * I_DIM, 2 * I_DIM, I_DIM,
      actr, I_DIM, (long)CAP * I_DIM, H_DIM);

  // shared gate_up + silu: B = ws_gu [1024][2048] fp32, u_off 1024
  gemm_gu<<<dim3(T_DIM / BMx, 1024 / 64, 1), dim3(256), 0, stream>>>(
      xbf, H_DIM, nullptr, nullptr, T_DIM,
      ws_gu, 0, 2048, 1024,
      acts, 1024, 0, H_DIM);

  // routed down -> Ya (gathered rows): B = w_dn [e][512][1024] fp32
  gemm_dn<bf16><<<dim3(CAP / BMx, H_DIM / BNx, E_NUM), dim3(256), 0, stream>>>(
      actr, (long)CAP * I_DIM, I_DIM, rowlist, counts, 0,
      w_dn, (long)I_DIM * H_DIM, H_DIM,
      (bf16*)Ya, H_DIM, I_DIM);

  // shared down -> out fp32 (full overwrite): B = ws_dn [1024][1024] fp32
  gemm_dn<float><<<dim3(T_DIM / BMx, H_DIM / BNx, 1), dim3(256), 0, stream>>>(
      acts, 0, 1024, nullptr, nullptr, T_DIM,
      ws_dn, 0, H_DIM,
      out, H_DIM, 1024);

  combine<<<dim3(T_DIM), dim3(256), 0, stream>>>(tkw, slot_a, Ya, out);
}

// Round 5
// 579.914 us; speedup vs baseline: 1.5451x; 1.0275x over previous
//
#include <hip/hip_runtime.h>
#include <math.h>

typedef __bf16 bf16;
typedef bf16 bf16x8 __attribute__((ext_vector_type(8)));
typedef float f32x4 __attribute__((ext_vector_type(4)));
typedef unsigned int u32;

#define T_DIM 1024
#define H_DIM 1024
#define E_NUM 64
#define I_DIM 512
#define KTOP 6
#define TKG 3
#define CAP 256
#define A_TOT (T_DIM * KTOP)
#define SCALE_F 2.5f

#define BMx 128
#define BNx 128
#define BKx 64  // k elems per tile
#define ABUF (BMx * BKx)  // 8192 elems = 16 KB per A buffer

// global_load_lds: per-lane global addr; LDS dest = wave-uniform base + lane*16.
typedef const u32 __attribute__((address_space(1)))* gas_t;
typedef u32 __attribute__((address_space(3)))* las_t;
__device__ __forceinline__ void gld16(const void* g, void* l) {
  __builtin_amdgcn_global_load_lds((gas_t)(unsigned long long)g,
                                   (las_t)(u32)(unsigned long long)l, 16, 0, 0);
}

// B-LDS swizzle: chunk stored at (kc ^ s(n)); conflict-free b128 writes, 2-way reads.
__device__ __forceinline__ int bswz(int n) {
  return ((n >> 2) ^ ((n & 3) << 1)) & 7;
}

// ---------------------------------------------------------------- convert x -> bf16
__global__ __launch_bounds__(256) void cvt_bf16(const float* __restrict__ in,
                                                bf16* __restrict__ out) {
  int i = (blockIdx.x * 256 + threadIdx.x) * 4;
  float4 v = *(const float4*)(in + i);
  bf16 __align__(8) t[4] = {(bf16)v.x, (bf16)v.y, (bf16)v.z, (bf16)v.w};
  *(uint2*)(out + i) = *(const uint2*)t;
}

// ---------------------------------------------------------------- router + grouped top-k
__global__ __launch_bounds__(256) void router_topk(const float* __restrict__ x,
                                                   const float* __restrict__ gw,
                                                   const float* __restrict__ bias,
                                                   int* __restrict__ topk_id,
                                                   float* __restrict__ topk_w) {
  __shared__ float part[4][64];
  const int t = blockIdx.x;
  const int tid = threadIdx.x;
  const int wave = tid >> 6, lane = tid & 63;
  const float* xr = x + (long)t * H_DIM + wave * 256;
  float acc = 0.f;
  for (int h = 0; h < 256; h += 4) {
    float4 xv = *(const float4*)(xr + h);
    int hh = wave * 256 + h;
    acc += xv.x * gw[(hh + 0) * E_NUM + lane];
    acc += xv.y * gw[(hh + 1) * E_NUM + lane];
    acc += xv.z * gw[(hh + 2) * E_NUM + lane];
    acc += xv.w * gw[(hh + 3) * E_NUM + lane];
  }
  part[wave][lane] = acc;
  __syncthreads();
  if (wave != 0) return;
  acc = part[0][lane] + part[1][lane] + part[2][lane] + part[3][lane];

  float score = 1.f / (1.f + __expf(-acc));  // sigmoid (weights come from this)
  float sel = score + bias[lane];            // biased score (selection only)

  // top-2 within each group of 8 lanes
  float m1 = sel, m2 = -INFINITY;
  #pragma unroll
  for (int off = 1; off < 8; off <<= 1) {
    float o1 = __shfl_xor(m1, off);
    float o2 = __shfl_xor(m2, off);
    float mn = fminf(m1, o1);
    float alt = (m1 >= o1) ? m2 : o2;
    m1 = fmaxf(m1, o1);
    m2 = fmaxf(mn, alt);
  }
  float gscore = m1 + m2;

  // top-3 groups (argmax, lowest-index tiebreak)
  const int my_g = lane >> 3;
  unsigned gmask = 0;
  float gv = ((lane & 7) == 0) ? gscore : -INFINITY;
  for (int r = 0; r < TKG; ++r) {
    float v = gv;
    int idx = my_g;
    #pragma unroll
    for (int off = 1; off < 64; off <<= 1) {
      float ov = __shfl_xor(v, off);
      int oi = __shfl_xor(idx, off);
      if (ov > v || (ov == v && oi < idx)) { v = ov; idx = oi; }
    }
    gmask |= 1u << idx;
    if (my_g == idx) gv = -INFINITY;
  }

  // top-6 experts within selected groups
  float cand = ((gmask >> my_g) & 1u) ? sel : -INFINITY;
  float wk[KTOP];
  int ik[KTOP];
  float wsum = 0.f;
  for (int r = 0; r < KTOP; ++r) {
    float v = cand;
    int idx = lane;
    #pragma unroll
    for (int off = 1; off < 64; off <<= 1) {
      float ov = __shfl_xor(v, off);
      int oi = __shfl_xor(idx, off);
      if (ov > v || (ov == v && oi < idx)) { v = ov; idx = oi; }
    }
    float w = __shfl(score, idx);  // weight from UN-biased score
    wk[r] = w; ik[r] = idx; wsum += w;
    if (lane == idx) cand = -INFINITY;
  }
  if (lane == 0) {
    float inv = 1.f / wsum;
    #pragma unroll
    for (int r = 0; r < KTOP; ++r) {
      topk_id[t * KTOP + r] = ik[r];
      topk_w[t * KTOP + r] = wk[r] * inv;
    }
  }
}

// ---------------------------------------------------------------- dispatch (ordered compaction)
__global__ __launch_bounds__(64) void dispatch(const int* __restrict__ topk_id,
                                               int* __restrict__ rowlist,
                                               int* __restrict__ slot_a,
                                               int* __restrict__ counts) {
  __shared__ int ids[A_TOT];
  const int e = blockIdx.x, lane = threadIdx.x;
  for (int i = lane; i < A_TOT; i += 64) ids[i] = topk_id[i];
  __syncthreads();
  int base = 0;
  for (int a0 = 0; a0 < A_TOT; a0 += 64) {
    int a = a0 + lane;
    bool m = (ids[a] == e);
    unsigned long long bal = __ballot(m);
    if (m) {
      int pos = base + __popcll(bal & ((1ull << lane) - 1ull));
      slot_a[a] = (pos < CAP) ? pos : -1;
      if (pos < CAP) rowlist[e * CAP + pos] = a;
    }
    base += __popcll(bal);
  }
  if (lane == 0) counts[e] = (base < CAP) ? base : CAP;
}

// ================================================================ 128x128 MFMA GEMM, pipelined:
// loads for tile k+1 issue AFTER barrier1 (inside MFMA section) so the pre-barrier2
// vmcnt(0) drain lands after ~32 MFMAs of cover. A double-buffered (gld16 into the
// idle half); B single-buffered (regs->LDS write happens after barrier2).

// ---------------------------------------------------------------- gate_up + fused SiLU*mul
__global__ __launch_bounds__(256) void gemm_gu(
    const bf16* __restrict__ X, int x_ld,
    const int* __restrict__ rows, const int* __restrict__ counts, int n_rows_fixed,
    const float* __restrict__ W, long w_estride, int ldb, int u_off,
    bf16* __restrict__ act, int act_ld, long act_estride, int kdim) {
  __shared__ union {
    struct { bf16 A[2 * ABUF]; bf16 B[BNx * BKx]; } st;  // 32 KB + 16 KB
    bf16 epi[BMx * 72];                                   // 18.4 KB repack
  } sm;
  const int e = blockIdx.z;
  const int n_rows = counts ? counts[e] : n_rows_fixed;
  const int m0 = blockIdx.x * BMx;
  if (m0 >= n_rows) return;
  const int nb = blockIdx.y;
  const int tid = threadIdx.x;
  const int w = tid >> 6, lane = tid & 63;
  const int q = lane >> 4, l16 = lane & 15;
  const int m_off = (w & 1) * 64;

  // ---- A staging geometry (global_load_lds)
  const int srow = w * 32 + (lane >> 3);
  const int gchunk = (lane & 7) ^ (lane >> 3);
  const bf16* pA[4];
  #pragma unroll
  for (int j = 0; j < 4; ++j) {
    int tr = m0 + srow + j * 8;
    int grow;
    if (rows) grow = (tr < n_rows) ? (rows[e * CAP + tr] / KTOP) : 0;
    else grow = tr;
    pA[j] = X + (long)grow * x_ld + gchunk * 8;
  }
  bf16* ldsA = sm.st.A + w * 2048 + lane * 8;

  // ---- B staging geometry (fp32 -> regs -> bf16 LDS transposed)
  const int kc = tid >> 5;          // 0..7 (k-chunk of 8 rows)
  const int n0 = (tid & 31) * 4;    // local col base 0..124
  const int gcol = (n0 < 64) ? (nb * 64 + n0) : (u_off + nb * 64 + (n0 - 64));
  const float* bcol = W + (long)e * w_estride + (long)kc * 8 * ldb + gcol;
  float4 bv[8];
  #pragma unroll
  for (int r = 0; r < 8; ++r) bv[r] = *(const float4*)(bcol + (long)r * ldb);

  // prologue: A(0) into buffer 0
  #pragma unroll
  for (int j = 0; j < 4; ++j) {
    gld16(pA[j], ldsA + j * 512);
    pA[j] += BKx;
  }

  f32x4 acc[4][4];
  #pragma unroll
  for (int i = 0; i < 4; ++i)
    #pragma unroll
    for (int j = 0; j < 4; ++j) acc[i][j] = (f32x4){0.f, 0.f, 0.f, 0.f};

  const int niter = kdim / BKx;
  for (int k = 0; k < niter; ++k) {
    const int p = k & 1;
    // stage B(k): regs -> LDS (4x ds_write_b128)
    #pragma unroll
    for (int j = 0; j < 4; ++j) {
      bf16 __align__(16) t8[8];
      #pragma unroll
      for (int r = 0; r < 8; ++r) t8[r] = (bf16)((const float*)&bv[r])[j];
      int n = n0 + j;
      *(uint4*)(sm.st.B + n * BKx + ((kc ^ bswz(n)) * 8)) = *(const uint4*)t8;
    }
    __syncthreads();  // drains ds_writes (+ prologue gld16 on k=0)

    // issue next-tile loads NOW: drained at the post-MFMA barrier (covered)
    if (k + 1 < niter) {
      const float* bnext = bcol + (long)(k + 1) * BKx * ldb;
      #pragma unroll
      for (int r = 0; r < 8; ++r) bv[r] = *(const float4*)(bnext + (long)r * ldb);
      #pragma unroll
      for (int j = 0; j < 4; ++j) {
        gld16(pA[j], ldsA + (1 - p) * ABUF + j * 512);
        pA[j] += BKx;
      }
    }

    #pragma unroll
    for (int kh = 0; kh < 2; ++kh) {
      bf16x8 a[4], b[4];
      const int co = ((kh * 4 + q) ^ (l16 & 7)) * 8;
      #pragma unroll
      for (int i = 0; i < 4; ++i)
        a[i] = *(const bf16x8*)(sm.st.A + p * ABUF + (m_off + i * 16 + l16) * BKx + co);
      #pragma unroll
      for (int j = 0; j < 4; ++j) {
        int nf = (j >> 1) * 64 + (w >> 1) * 32 + (j & 1) * 16;  // gate: j<2; up: j>=2
        int n = nf + l16;
        b[j] = *(const bf16x8*)(sm.st.B + n * BKx + (((kh * 4 + q) ^ bswz(n)) * 8));
      }
      #pragma unroll
      for (int i = 0; i < 4; ++i)
        #pragma unroll
        for (int j = 0; j < 4; ++j)
          acc[i][j] = __builtin_amdgcn_mfma_f32_16x16x32_bf16(a[i], b[j], acc[i][j], 0, 0, 0);
    }
    __syncthreads();  // drains next-tile gld16 + bv loads, covered by the 32 MFMAs
  }

  // SiLU(g)*u in registers: g=acc[i][j], u=acc[i][j+2] (same row, col+64)
  const int c_base = (w >> 1) * 32;
  #pragma unroll
  for (int i = 0; i < 4; ++i)
    #pragma unroll
    for (int j = 0; j < 2; ++j)
      #pragma unroll
      for (int r = 0; r < 4; ++r) {
        float g = acc[i][j][r], uu = acc[i][j + 2][r];
        float s = g / (1.f + __expf(-g));
        sm.epi[(m_off + i * 16 + q * 4 + r) * 72 + c_base + j * 16 + l16] = (bf16)(s * uu);
      }
  __syncthreads();
  #pragma unroll
  for (int p = 0; p < 4; ++p) {
    int row = p * 32 + (tid >> 3);
    int c0 = (tid & 7) * 8;
    uint4 v = *(const uint4*)(sm.epi + row * 72 + c0);
    *(uint4*)(act + (long)e * act_estride + (long)(m0 + row) * act_ld + nb * 64 + c0) = v;
  }
}

// ---------------------------------------------------------------- down GEMM
template <typename OutT>
__global__ __launch_bounds__(256) void gemm_dn(
    const bf16* __restrict__ Abase, long a_estride, int a_ld,
    const int* __restrict__ rowsO, const int* __restrict__ counts, int n_rows_fixed,
    const float* __restrict__ W, long w_estride, int ldb,
    OutT* __restrict__ Out, int out_ld, int kdim) {
  __shared__ union {
    struct { bf16 A[2 * ABUF]; bf16 B[BNx * BKx]; } st;  // 48 KB
    bf16 epi[BMx * 136];  // 34.8 KB bf16 repack
  } sm;
  const int e = blockIdx.z;
  const int n_rows = counts ? counts[e] : n_rows_fixed;
  const int m0 = blockIdx.x * BMx;
  if (m0 >= n_rows) return;
  const int nb = blockIdx.y;
  const int tid = threadIdx.x;
  const int w = tid >> 6, lane = tid & 63;
  const int q = lane >> 4, l16 = lane & 15;
  const int m_off = (w & 1) * 64;
  const int n_off = (w >> 1) * 64;

  const int srow = w * 32 + (lane >> 3);
  const int gchunk = (lane & 7) ^ (lane >> 3);
  const bf16* pA[4];
  #pragma unroll
  for (int j = 0; j < 4; ++j)
    pA[j] = Abase + (long)e * a_estride + (long)(m0 + srow + j * 8) * a_ld + gchunk * 8;
  bf16* ldsA = sm.st.A + w * 2048 + lane * 8;

  const int kc = tid >> 5;
  const int n0 = (tid & 31) * 4;
  const float* bcol = W + (long)e * w_estride + (long)kc * 8 * ldb + nb * BNx + n0;
  float4 bv[8];
  #pragma unroll
  for (int r = 0; r < 8; ++r) bv[r] = *(const float4*)(bcol + (long)r * ldb);

  #pragma unroll
  for (int j = 0; j < 4; ++j) {
    gld16(pA[j], ldsA + j * 512);
    pA[j] += BKx;
  }

  f32x4 acc[4][4];
  #pragma unroll
  for (int i = 0; i < 4; ++i)
    #pragma unroll
    for (int j = 0; j < 4; ++j) acc[i][j] = (f32x4){0.f, 0.f, 0.f, 0.f};

  const int niter = kdim / BKx;
  for (int k = 0; k < niter; ++k) {
    const int p = k & 1;
    #pragma unroll
    for (int j = 0; j < 4; ++j) {
      bf16 __align__(16) t8[8];
      #pragma unroll
      for (int r = 0; r < 8; ++r) t8[r] = (bf16)((const float*)&bv[r])[j];
      int n = n0 + j;
      *(uint4*)(sm.st.B + n * BKx + ((kc ^ bswz(n)) * 8)) = *(const uint4*)t8;
    }
    __syncthreads();

    if (k + 1 < niter) {
      const float* bnext = bcol + (long)(k + 1) * BKx * ldb;
      #pragma unroll
      for (int r = 0; r < 8; ++r) bv[r] = *(const float4*)(bnext + (long)r * ldb);
      #pragma unroll
      for (int j = 0; j < 4; ++j) {
        gld16(pA[j], ldsA + (1 - p) * ABUF + j * 512);
        pA[j] += BKx;
      }
    }

    #pragma unroll
    for (int kh = 0; kh < 2; ++kh) {
      bf16x8 a[4], b[4];
      const int co = ((kh * 4 + q) ^ (l16 & 7)) * 8;
      #pragma unroll
      for (int i = 0; i < 4; ++i)
        a[i] = *(const bf16x8*)(sm.st.A + p * ABUF + (m_off + i * 16 + l16) * BKx + co);
      #pragma unroll
      for (int j = 0; j < 4; ++j) {
        int n = n_off + j * 16 + l16;
        b[j] = *(const bf16x8*)(sm.st.B + n * BKx + (((kh * 4 + q) ^ bswz(n)) * 8));
      }
      #pragma unroll
      for (int i = 0; i < 4; ++i)
        #pragma unroll
        for (int j = 0; j < 4; ++j)
          acc[i][j] = __builtin_amdgcn_mfma_f32_16x16x32_bf16(a[i], b[j], acc[i][j], 0, 0, 0);
    }
    __syncthreads();
  }

  if constexpr (sizeof(OutT) == 4) {
    #pragma unroll
    for (int i = 0; i < 4; ++i)
      #pragma unroll
      for (int j = 0; j < 4; ++j)
        #pragma unroll
        for (int r = 0; r < 4; ++r) {
          int row = m0 + m_off + i * 16 + q * 4 + r;
          Out[(long)row * out_ld + nb * BNx + n_off + j * 16 + l16] = acc[i][j][r];
        }
  } else {
    #pragma unroll
    for (int i = 0; i < 4; ++i)
      #pragma unroll
      for (int j = 0; j < 4; ++j)
        #pragma unroll
        for (int r = 0; r < 4; ++r)
          sm.epi[(m_off + i * 16 + q * 4 + r) * 136 + n_off + j * 16 + l16] = (bf16)acc[i][j][r];
    __syncthreads();
    #pragma unroll
    for (int p = 0; p < 8; ++p) {
      int row = p * 16 + (tid >> 4);
      int c0 = (tid & 15) * 8;
      if (m0 + row < n_rows) {
        long orow = rowsO ? (long)rowsO[e * CAP + m0 + row] : (long)(m0 + row);
        *(uint4*)((bf16*)Out + orow * out_ld + nb * BNx + c0) =
            *(const uint4*)(sm.epi + row * 136 + c0);
      }
    }
  }
}

// ---------------------------------------------------------------- combine
__global__ __launch_bounds__(256) void combine(const float* __restrict__ tkw,
                                               const int* __restrict__ slot_a,
                                               const bf16* __restrict__ Ya,
                                               float* __restrict__ out) {
  const int t = blockIdx.x, tid = threadIdx.x;
  long o = (long)t * H_DIM + tid * 4;
  float4 v = *(float4*)(out + o);  // shared-expert result already here
  float a0 = v.x, a1 = v.y, a2 = v.z, a3 = v.w;
  #pragma unroll
  for (int k = 0; k < KTOP; ++k) {
    int a = t * KTOP + k;
    if (slot_a[a] >= 0) {
      float w = tkw[a] * SCALE_F;
      const bf16* yr = Ya + (long)a * H_DIM + tid * 4;
      uint2 yv = *(const uint2*)yr;
      bf16 __align__(8) yb[4];
      *(uint2*)yb = yv;
      a0 += w * (float)yb[0];
      a1 += w * (float)yb[1];
      a2 += w * (float)yb[2];
      a3 += w * (float)yb[3];
    }
  }
  *(float4*)(out + o) = make_float4(a0, a1, a2, a3);
}

// ---------------------------------------------------------------- launch
extern "C" void kernel_launch(void* const* d_in, const int* in_sizes, int n_in,
                              void* d_out, int out_size, void* d_ws, size_t ws_size,
                              hipStream_t stream) {
  const float* x     = (const float*)d_in[0];
  const float* gw    = (const float*)d_in[1];
  const float* bias  = (const float*)d_in[2];
  const float* w_gu  = (const float*)d_in[3];
  const float* w_dn  = (const float*)d_in[4];
  const float* ws_gu = (const float*)d_in[5];
  const float* ws_dn = (const float*)d_in[6];
  float* out = (float*)d_out;
  char* ws = (char*)d_ws;

  // workspace layout (bytes), total ~34 MB
  bf16* xbf     = (bf16*)(ws + 0);           //  2,097,152
  bf16* acts    = (bf16*)(ws + 2097152);     //  2,097,152  shared act [T][1024]
  bf16* actr    = (bf16*)(ws + 4194304);     // 16,777,216  routed act [E][CAP][512]
  bf16* Ya      = (bf16*)(ws + 20971520);    // 12,582,912  routed out [A_TOT][1024]
  int*  tki     = (int*)(ws + 33554432);     // 24,576
  float* tkw    = (float*)(ws + 33579008);   // 24,576
  int*  rowlist = (int*)(ws + 33603584);     // 65,536
  int*  slot_a  = (int*)(ws + 33669120);     // 24,576
  int*  counts  = (int*)(ws + 33693696);     // 1,024

  cvt_bf16<<<dim3((T_DIM * H_DIM) / 1024), dim3(256), 0, stream>>>(x, xbf);
  router_topk<<<dim3(T_DIM), dim3(256), 0, stream>>>(x, gw, bias, tki, tkw);
  dispatch<<<dim3(E_NUM), dim3(64), 0, stream>>>(tki, rowlist, slot_a, counts);

  // routed gate_up + silu: B = w_gu [e][1024][1024] fp32, gate cols 0..511, up 512..1023
  gemm_gu<<<dim3(CAP / BMx, I_DIM / 64, E_NUM), dim3(256), 0, stream>>>(
      xbf, H_DIM, rowlist, counts, 0,
      w_gu, (long)H_DIM * 2 * I_DIM, 2 * I_DIM, I_DIM,
      actr, I_DIM, (long)CAP * I_DIM, H_DIM);

  // shared gate_up + silu: B = ws_gu [1024][2048] fp32, u_off 1024
  gemm_gu<<<dim3(T_DIM / BMx, 1024 / 64, 1), dim3(256), 0, stream>>>(
      xbf, H_DIM, nullptr, nullptr, T_DIM,
      ws_gu, 0, 2048, 1024,
      acts, 1024, 0, H_DIM);

  // routed down -> Ya (gathered rows): B = w_dn [e][512][1024] fp32
  gemm_dn<bf16><<<dim3(CAP / BMx, H_DIM / BNx, E_NUM), dim3(256), 0, stream>>>(
      actr, (long)CAP * I_DIM, I_DIM, rowlist, counts, 0,
      w_dn, (long)I_DIM * H_DIM, H_DIM,
      (bf16*)Ya, H_DIM, I_DIM);

  // shared down -> out fp32 (full overwrite): B = ws_dn [1024][1024] fp32
  gemm_dn<float><<<dim3(T_DIM / BMx, H_DIM / BNx, 1), dim3(256), 0, stream>>>(
      acts, 0, 1024, nullptr, nullptr, T_DIM,
      ws_dn, 0, H_DIM,
      out, H_DIM, 1024);

  combine<<<dim3(T_DIM), dim3(256), 0, stream>>>(tkw, slot_a, Ya, out);
}